// Round 14
// baseline (186.256 us; speedup 1.0000x reference)
//
#include <hip/hip_runtime.h>
#include <math.h>

#define NB    1024
#define NC    62
#define NBAND 5
#define NOUT  16
#define NHID  10
#define ZSTR  68   // zS row stride in f16
#define XTW   34   // XcT row stride in u32 (64 f16 + pad)
#define PHW   66   // pH row stride in f16

typedef __attribute__((ext_vector_type(2))) float f32x2;
typedef __attribute__((ext_vector_type(4))) float f32x4;
typedef __attribute__((ext_vector_type(2))) _Float16 f16x2;
typedef __attribute__((ext_vector_type(8))) _Float16 f16x8;
typedef __attribute__((ext_vector_type(2))) __fp16 fp16v2;   // cvt_pkrtz result type
#define FMA2(a, b, c) __builtin_elementwise_fma((a), (b), (c))
#define DOT2(a, b, c) __builtin_amdgcn_fdot2((a), (b), (c), false)

__device__ __forceinline__ f16x2 u2h(unsigned int u) { return __builtin_bit_cast(f16x2, u); }
__device__ __forceinline__ unsigned int pk2u(float x, float y) {
  const fp16v2 v = __builtin_amdgcn_cvt_pkrtz(x, y);
  return __builtin_bit_cast(unsigned int, v);
}

// =====================================================================
// Kernel A (v13): gate-cancelled SPD, MFMA SYRK (v12-validated), with
// COALESCED pcc read: each (b,k) block reads pcc[b] as dense float4s
// (each 16B quad holds <=1 band-k element), relu+f16-scatters into
// pH[i][j] LDS, then the center/pack pipeline gathers from LDS.
// 5 sibling bands are co-XCD -> L2 dedups the 5x logical re-read.
// =====================================================================
__global__ __launch_bounds__(256) void k_spd(
    const float* __restrict__ pcc, const float* __restrict__ Aadj,
    const float* __restrict__ hlin_w, const float* __restrict__ elin_w,
    const float* __restrict__ att_w1,
    _Float16* __restrict__ comH, unsigned int* __restrict__ lwHg,
    unsigned int* __restrict__ w1Hg, float* __restrict__ rsumG) {
  const int bk = (blockIdx.x & 7) * 640 + (blockIdx.x >> 3);  // XCD swizzle, 5120%8==0
  const int b = bk / NBAND, k = bk % NBAND;
  __shared__ __align__(16) unsigned int XcT[64 * XTW];   // 8704 B, f16 [c][i]
  __shared__ __align__(4)  _Float16 pH[NC * PHW];        // 8184 B, relu(pcc band k)
  __shared__ float red4a[4], red4b[4];
  const int tid = threadIdx.x;
  const int wave = tid >> 6, lane = tid & 63;
  const int p = tid >> 3, q8 = tid & 7, c0 = q8 * 8;
  const bool act = (p < 31);
  const int r0 = 2 * p, r1 = r0 + 1;
  const int mrow = lane & 15, g = lane >> 4;

  float ld0[8], ld1[8];   // src0 centered values
  float lA0[8], lA1[8];   // Aadj prefetch / src1 centered values

  // center in regs; sq -> red[wave]. Inactive threads produce zeros.
  auto center = [&](float (&a0)[8], float (&a1)[8], float* red) -> void {
    float s0 = 0.f, s1 = 0.f;
#pragma unroll
    for (int u = 0; u < 8; ++u) { s0 += a0[u]; s1 += a1[u]; }
    s0 += __shfl_xor(s0, 1, 64); s0 += __shfl_xor(s0, 2, 64); s0 += __shfl_xor(s0, 4, 64);
    s1 += __shfl_xor(s1, 1, 64); s1 += __shfl_xor(s1, 2, 64); s1 += __shfl_xor(s1, 4, 64);
    const float m0 = s0 * (1.f / NC), m1 = s1 * (1.f / NC);
    float sq = 0.f;
#pragma unroll
    for (int u = 0; u < 8; ++u) {
      const bool in = act && (c0 + u < NC);
      const float cv0 = in ? (a0[u] - m0) : 0.f;
      const float cv1 = in ? (a1[u] - m1) : 0.f;
      a0[u] = cv0;
      a1[u] = cv1;
      sq += cv0 * cv0 + cv1 * cv1;
    }
#pragma unroll
    for (int off = 1; off < 64; off <<= 1) sq += __shfl_xor(sq, off, 64);
    if (lane == 0) red[wave] = sq;
  };

  // scaled f16 pack + transpose write: XcT[c0+u][p] = {sc*a0[u], sc*a1[u]}
  auto xct_write = [&](const float (&a0)[8], const float (&a1)[8], float sc) -> void {
#pragma unroll
    for (int u = 0; u < 8; ++u)
      XcT[(c0 + u) * XTW + p] = pk2u(sc * a0[u], sc * a1[u]);
  };

  // MFMA fragment from XcT row: lane holds 8 f16 at k = 32s+8g..+7
  auto fragread = [&](int row, int s) -> f16x8 {
    const unsigned int* pp = &XcT[row * XTW + 16 * s + 4 * g];
    const uint2 a = *reinterpret_cast<const uint2*>(pp);
    const uint2 b2 = *reinterpret_cast<const uint2*>(pp + 2);
    const uint4 v = make_uint4(a.x, a.y, b2.x, b2.y);
    return __builtin_bit_cast(f16x8, v);
  };

  // ---- Phase A: coalesced pcc[b] read + band-k extraction -> pH
  {
    const float4* src = reinterpret_cast<const float4*>(pcc + (size_t)b * (NC * NC * NBAND));
#pragma unroll
    for (int it = 0; it < 19; ++it) {
      const int fidx = tid + it * 256;
      if (fidx < 4805) {                       // 19220 floats / 4
        const float4 v = src[fidx];
        const int idx0 = 4 * fidx;
        const int e = (k - (idx0 % 5) + 5) % 5;
        if (e < 4) {
          const int gidx = idx0 + e;
          const int i = gidx / (NC * NBAND);
          const int j = (gidx - i * (NC * NBAND)) / NBAND;
          const float val = (e == 0) ? v.x : (e == 1) ? v.y : (e == 2) ? v.z : v.w;
          pH[i * PHW + j] = (_Float16)fmaxf(val, 0.f);
        }
      }
    }
  }

  // prefetch src1 = Aadj rows (coalesced float2; lands under phases A/B)
#pragma unroll
  for (int u = 0; u < 8; ++u) { lA0[u] = 0.f; lA1[u] = 0.f; }
  if (act) {
    const float* a0p = Aadj + ((size_t)(b * NBAND + k) * NC + r0) * NC + c0;
    const float* a1p = Aadj + ((size_t)(b * NBAND + k) * NC + r1) * NC + c0;
#pragma unroll
    for (int e = 0; e < 4; ++e) {
      const int c = c0 + 2 * e;
      if (c + 1 < NC) {
        const float2 v0 = *reinterpret_cast<const float2*>(a0p + 2 * e);
        const float2 v1 = *reinterpret_cast<const float2*>(a1p + 2 * e);
        lA0[2 * e] = v0.x; lA0[2 * e + 1] = v0.y;
        lA1[2 * e] = v1.x; lA1[2 * e + 1] = v1.y;
      } else if (c < NC) {
        lA0[2 * e] = a0p[2 * e];
        lA1[2 * e] = a1p[2 * e];
      }
    }
  }
  __syncthreads();   // (A) pH ready

  // ---- Phase B: gather rows from pH, center
#pragma unroll
  for (int u = 0; u < 8; ++u) { ld0[u] = 0.f; ld1[u] = 0.f; }
  if (act) {
#pragma unroll
    for (int u = 0; u < 8; ++u) {
      const int c = c0 + u;
      if (c < NC) {
        ld0[u] = (float)pH[r0 * PHW + c];
        ld1[u] = (float)pH[r1 * PHW + c];
      }
    }
  }
  center(ld0, ld1, red4a);
  __syncthreads();   // (1) red4a ready

  const float tra0 = red4a[0] + red4a[1] + red4a[2] + red4a[3];
  xct_write(ld0, ld1, sqrtf(0.5f / tra0));
  __syncthreads();   // (2) XcT(src0) ready

  // ---- MFMA src0: G rows 16*wave..+15, all 4 col-tiles
  f32x4 acc[4];
#pragma unroll
  for (int n = 0; n < 4; ++n) acc[n] = (f32x4){0.f, 0.f, 0.f, 0.f};
  {
    const f16x8 A0 = fragread(16 * wave + mrow, 0);
    const f16x8 A1 = fragread(16 * wave + mrow, 1);
#pragma unroll
    for (int n = 0; n < 4; ++n) {
      const f16x8 B0 = fragread(16 * n + mrow, 0);
      const f16x8 B1 = fragread(16 * n + mrow, 1);
      acc[n] = __builtin_amdgcn_mfma_f32_16x16x32_f16(A0, B0, acc[n], 0, 0, 0);
      acc[n] = __builtin_amdgcn_mfma_f32_16x16x32_f16(A1, B1, acc[n], 0, 0, 0);
    }
  }

  // ---- src1: relu + center (overlaps MFMA on the VALU pipe)
#pragma unroll
  for (int u = 0; u < 8; ++u) { lA0[u] = fmaxf(lA0[u], 0.f); lA1[u] = fmaxf(lA1[u], 0.f); }
  center(lA0, lA1, red4b);
  __syncthreads();   // (3) MFMA src0 reads done; red4b ready

  const float tra1 = red4b[0] + red4b[1] + red4b[2] + red4b[3];
  xct_write(lA0, lA1, sqrtf(0.5f / tra1));
  __syncthreads();   // (4) XcT(src1) ready

  {
    const f16x8 A0 = fragread(16 * wave + mrow, 0);
    const f16x8 A1 = fragread(16 * wave + mrow, 1);
#pragma unroll
    for (int n = 0; n < 4; ++n) {
      const f16x8 B0 = fragread(16 * n + mrow, 0);
      const f16x8 B1 = fragread(16 * n + mrow, 1);
      acc[n] = __builtin_amdgcn_mfma_f32_16x16x32_f16(A0, B0, acc[n], 0, 0, 0);
      acc[n] = __builtin_amdgcn_mfma_f32_16x16x32_f16(A1, B1, acc[n], 0, 0, 0);
    }
  }

  // ---- epilogue: diag + f16 store. r = 16*wave+4g+reg, col = 16n+mrow.
#pragma unroll
  for (int reg = 0; reg < 4; ++reg) {
    const int r = 16 * wave + 4 * g + reg;
#pragma unroll
    for (int n = 0; n < 4; ++n) {
      float v = acc[n][reg];
      if (n == wave && mrow == 4 * g + reg) v += 1e-5f;   // diagonal
      comH[(size_t)bk * 4096 + r * 64 + 16 * n + mrow] = (_Float16)v;
    }
  }

  // ---- block 0 epilogue: lwHg row-major f16 [br][o][c], w1H, row sums
  if (blockIdx.x == 0) {
    for (int t = tid; t < 2 * 64 * 32; t += 256) {
      const int brx = t >> 11, rem = t & 2047, o = rem >> 5, cp = rem & 31;
      const float* lwsrc = brx ? elin_w : hlin_w;
      float lo = 0.f, hi = 0.f;
      if (o < NC) {
        const int c = 2 * cp;
        if (c < NC)     lo = lwsrc[o * NC + c];
        if (c + 1 < NC) hi = lwsrc[o * NC + c + 1];
      }
      lwHg[t] = pk2u(lo, hi);   // [br][o][c-pair] row-major
    }
    for (int t = tid; t < NHID * 32; t += 256) {
      const int h = t >> 5, op = t & 31;
      const float lo = (2 * op < NC) ? att_w1[h * NC + 2 * op] : 0.f;
      const float hi = (2 * op + 1 < NC) ? att_w1[h * NC + 2 * op + 1] : 0.f;
      w1Hg[t] = pk2u(lo, hi);
    }
    if (tid < 64) {
      float sh = 0.f, se = 0.f;
      if (tid < NC) {
        for (int c = 0; c < NC; ++c) { sh += hlin_w[tid * NC + c]; se += elin_w[tid * NC + c]; }
      }
      rsumG[tid] = sh;
      rsumG[64 + tid] = se;
    }
  }
}

// =====================================================================
// Kernel B (v11, MFMA): unchanged (validated).
// =====================================================================
__global__ __launch_bounds__(256, 2) void k_branch(
    const _Float16* __restrict__ comH, const unsigned int* __restrict__ lwHg,
    const unsigned int* __restrict__ w1Hg, const float* __restrict__ rsumG,
    const float* __restrict__ hconv_w, const float* __restrict__ hconv_b,
    const float* __restrict__ hlin_b,
    const float* __restrict__ econv_w, const float* __restrict__ econv_b,
    const float* __restrict__ elin_b,
    const float* __restrict__ att_b1,  const float* __restrict__ att_w2,
    float* __restrict__ hiddenO, float* __restrict__ essentialO) {
  const int bid = (blockIdx.x & 7) * 256 + (blockIdx.x >> 3);  // XCD swizzle
  const int b = bid >> 1, br = bid & 1;

  const float* __restrict__ cw = br ? econv_w : hconv_w;
  const float* __restrict__ cb = br ? econv_b : hconv_b;
  const float* __restrict__ lb = br ? elin_b : hlin_b;
  float* __restrict__ outp = br ? essentialO : hiddenO;

  __shared__ __align__(16) unsigned int comS[64 * 32];     // 8 KB, XOR-swizzled
  __shared__ __align__(16) _Float16 zS[4][16 * ZSTR];      // 8.7 KB, per-wave
  __shared__ __align__(16) unsigned int w1S[NHID * 32];    // o-pair f16
  __shared__ float scoreS[4][16];
  __shared__ float b1S[16], w2S[16], cwS[8], cbS[8];

  const int tid = threadIdx.x;
  const int w = tid >> 6, lane = tid & 63;
  const int mrow = lane & 15;       // A-row within strip / C col-within-tile
  const int g = lane >> 4;          // k-group / C row-group

  // ---- param fills (block-wide -> one barrier)
  for (int t = tid; t < NHID * 32; t += 256) w1S[t] = w1Hg[t];
  if (tid < NHID) { b1S[tid] = att_b1[tid]; w2S[tid] = att_w2[tid]; }
  if (tid < NBAND) { cwS[tid] = cw[tid]; cbS[tid] = cb[tid]; }

  // ---- B-frags in registers (band-invariant): B[s][n], col = 16n+mrow
  f16x8 Bf[2][4];
  float rsumR[4], lbR[4];
#pragma unroll
  for (int n = 0; n < 4; ++n) {
    const int col = 16 * n + mrow;
    rsumR[n] = rsumG[br * 64 + col];
    lbR[n] = (col < NC) ? lb[col] : 0.f;
#pragma unroll
    for (int s = 0; s < 2; ++s) {
      const uint4 v = *reinterpret_cast<const uint4*>(lwHg + br * 2048 + col * 32 + s * 16 + g * 4);
      Bf[s][n] = __builtin_bit_cast(f16x8, v);
    }
  }
  __syncthreads();   // w1S/b1S/w2S/cwS/cbS visible to all waves

  // ---- staging: wave w stages ITS strip rows 16w..16w+15 (128 uint4).
  const uint4* gsrc = reinterpret_cast<const uint4*>(comH + (size_t)(b * NBAND) * 4096);
  uint4 pf[2];
  auto stage_issue = [&](int band) {
#pragma unroll
    for (int i = 0; i < 2; ++i) pf[i] = gsrc[band * 512 + w * 128 + i * 64 + lane];
  };
  auto stage_write = [&]() {
#pragma unroll
    for (int i = 0; i < 2; ++i) {
      const int idx = i * 64 + lane;          // within strip: 0..127
      const int row = 16 * w + (idx >> 3), slot = idx & 7;
      const int sb = (slot * 16) ^ ((row & 7) << 4);   // swizzled byte in row
      *reinterpret_cast<uint4*>(comS + row * 32 + sb / 4) = pf[i];
    }
  };

  auto a_frag = [&](int s) -> f16x8 {
    const int row = 16 * w + mrow;
    const int sb = (64 * s + 16 * g) ^ ((row & 7) << 4);
    return __builtin_bit_cast(f16x8, *reinterpret_cast<const uint4*>(comS + row * 32 + sb / 4));
  };

  stage_issue(0);
  stage_write();

  f32x4 oacc[4];
#pragma unroll
  for (int n = 0; n < 4; ++n) oacc[n] = (f32x4){0.f, 0.f, 0.f, 0.f};
  float denom[4] = {0.f, 0.f, 0.f, 0.f};
  float mrun[4] = {-1e30f, -1e30f, -1e30f, -1e30f};

  _Float16* zSw = &zS[w][0];   // wave-private
  const int rowz = lane >> 2, qz = lane & 3;   // scorer mapping

#pragma unroll 1
  for (int kb = 0; kb < NBAND; ++kb) {
    if (kb < NBAND - 1) stage_issue(kb + 1);   // T14: issue early

    // ---- MFMA GEMM: acc[n] = A(strip) x B[n], K=64 in 2 steps
    const f16x8 A0 = a_frag(0);
    const f16x8 A1 = a_frag(1);
    f32x4 acc[4];
#pragma unroll
    for (int n = 0; n < 4; ++n) {
      acc[n] = __builtin_amdgcn_mfma_f32_16x16x32_f16(A0, Bf[0][n], (f32x4){0.f, 0.f, 0.f, 0.f}, 0, 0, 0);
      acc[n] = __builtin_amdgcn_mfma_f32_16x16x32_f16(A1, Bf[1][n], acc[n], 0, 0, 0);
    }

    if (kb < NBAND - 1) stage_write();   // in-order DS: lands after A reads

    // ---- sigmoid in C-layout regs; write z to wave-private zS (f16)
    const float ck = cwS[kb], dk = cbS[kb];
#pragma unroll
    for (int n = 0; n < 4; ++n) {
      const float base = dk * rsumR[n] + lbR[n];
#pragma unroll
      for (int reg = 0; reg < 4; ++reg) {
        const float zv = 1.f / (1.f + __expf(-(ck * acc[n][reg] + base)));
        acc[n][reg] = zv;
        zSw[(4 * g + reg) * ZSTR + 16 * n + mrow] = (_Float16)zv;
      }
    }

    // ---- scorer over zS rows: row = lane>>2, q = lane&3
    {
      const _Float16* zr = zSw + rowz * ZSTR + qz * 16;
      unsigned int zh[8];
#pragma unroll
      for (int j = 0; j < 4; ++j) {
        const uint2 v = *reinterpret_cast<const uint2*>(zr + 4 * j);  // 8B-aligned
        zh[2 * j] = v.x;
        zh[2 * j + 1] = v.y;
      }
      float sacc = 0.f;
#pragma unroll
      for (int t = 0; t < 5; ++t) {
        const int hA = 2 * t, hB = 2 * t + 1;
        const uint4 wa0 = *reinterpret_cast<const uint4*>(w1S + hA * 32 + qz * 8);
        const uint4 wa1 = *reinterpret_cast<const uint4*>(w1S + hA * 32 + qz * 8 + 4);
        const uint4 wb0 = *reinterpret_cast<const uint4*>(w1S + hB * 32 + qz * 8);
        const uint4 wb1 = *reinterpret_cast<const uint4*>(w1S + hB * 32 + qz * 8 + 4);
        const unsigned int wau[8] = {wa0.x, wa0.y, wa0.z, wa0.w, wa1.x, wa1.y, wa1.z, wa1.w};
        const unsigned int wbu[8] = {wb0.x, wb0.y, wb0.z, wb0.w, wb1.x, wb1.y, wb1.z, wb1.w};
        float pA = 0.f, pB = 0.f;
#pragma unroll
        for (int u = 0; u < 8; ++u) {
          pA = DOT2(u2h(zh[u]), u2h(wau[u]), pA);
          pB = DOT2(u2h(zh[u]), u2h(wbu[u]), pB);
        }
        pA += __shfl_xor(pA, 1, 64); pA += __shfl_xor(pA, 2, 64);
        pB += __shfl_xor(pB, 1, 64); pB += __shfl_xor(pB, 2, 64);
        const float exA = __expf(2.f * (pA + b1S[hA]));
        const float exB = __expf(2.f * (pB + b1S[hB]));
        sacc += w2S[hA] * (1.f - 2.f / (exA + 1.f));
        sacc += w2S[hB] * (1.f - 2.f / (exB + 1.f));
      }
      if (qz == 0) scoreS[w][rowz] = sacc;
    }

    // ---- online softmax on C-layout accs (rows 4g+reg)
#pragma unroll
    for (int reg = 0; reg < 4; ++reg) {
      const float sc = scoreS[w][4 * g + reg];     // in-order after write
      const float nm = fmaxf(mrun[reg], sc);
      const float f = __expf(mrun[reg] - nm), e = __expf(sc - nm);
      denom[reg] = denom[reg] * f + e;
#pragma unroll
      for (int n = 0; n < 4; ++n)
        oacc[n][reg] = oacc[n][reg] * f + e * acc[n][reg];
      mrun[reg] = nm;
    }
  }

  // ---- store: r = 16w + 4g + reg, col = 16n + mrow
#pragma unroll
  for (int reg = 0; reg < 4; ++reg) {
    const int r = 16 * w + 4 * g + reg;
    if (r < NC) {
      const float inv = 1.f / denom[reg];
#pragma unroll
      for (int n = 0; n < 4; ++n) {
        const int col = 16 * n + mrow;
        if (col < NC) outp[(size_t)b * (NC * NC) + r * NC + col] = oacc[n][reg] * inv;
      }
    }
  }
}

// =====================================================================
// Kernel C: Chebyshev GCN + feature + 992->62 FC (unchanged).
// =====================================================================
__global__ __launch_bounds__(256) void k_cheb_fc(
    const float* __restrict__ de, const float* __restrict__ hidden,
    const float* __restrict__ essential, const float* __restrict__ gc_w,
    const float* __restrict__ gc_b, const float* __restrict__ fc_w,
    const float* __restrict__ fc_b, float* __restrict__ zmat) {
  const int b = blockIdx.x;
  __shared__ float hidS[NC * NC], essS[NC * NC];
  __shared__ float t0S[NC * NOUT], t1S[NC * NOUT];
  __shared__ float featS[NC * NOUT];
  __shared__ float deS[NC * NBAND];
  __shared__ float red2[256];
  const int tid = threadIdx.x;

  for (int t = tid; t < NC * NBAND; t += 256) deS[t] = de[b * NC * NBAND + t];
  for (int t = tid; t < NC * NC; t += 256) {
    hidS[t] = hidden[b * NC * NC + t];
    essS[t] = essential[b * NC * NC + t];
  }
  __syncthreads();
  for (int t = tid; t < NC * NOUT; t += 256) {
    const int i = t / NOUT, f = t % NOUT;
    float a0 = gc_b[f];
    float a1 = 0.f;
#pragma unroll
    for (int qq = 0; qq < NBAND; ++qq) {
      const float d = deS[i * NBAND + qq];
      a0 += d * gc_w[qq * NOUT + f];
      a1 += d * gc_w[(NBAND + qq) * NOUT + f];
    }
    t0S[t] = a0;
    t1S[t] = a1;
  }
  __syncthreads();
  for (int t = tid; t < NC * NOUT; t += 256) {
    const int i = t / NOUT, f = t % NOUT;
    float sh = 0.f, se = 0.f;
    for (int jj = 0; jj < NC; ++jj) {
      const float t1 = t1S[jj * NOUT + f];
      sh += hidS[i * NC + jj] * t1;
      se += essS[i * NC + jj] * t1;
    }
    const float gb1 = gc_b[NOUT + f];
    const float h = fmaxf(t0S[t] + sh + gb1, 0.f);
    const float e = fmaxf(t0S[t] + se + gb1, 0.f);
    featS[t] = 0.5f * (h + e);
  }
  __syncthreads();
  {
    const int n = tid >> 2, qq = tid & 3;
    float p = 0.f;
    if (n < NC) {
      const float* fw = fc_w + n * (NC * NOUT) + qq * 248;
      const float* fs = featS + qq * 248;
      for (int m = 0; m < 248; ++m) p += fs[m] * fw[m];
    }
    red2[tid] = p;
    __syncthreads();
    if (tid < NC) {
      const float z = red2[tid * 4] + red2[tid * 4 + 1] + red2[tid * 4 + 2] + red2[tid * 4 + 3] + fc_b[tid];
      zmat[b * NC + tid] = z;
    }
  }
}

// =====================================================================
// Kernel D1: batch-norm statistics (unchanged).
// =====================================================================
__global__ __launch_bounds__(256) void k_bnstats(
    const float* __restrict__ zmat, const float* __restrict__ bn_g,
    const float* __restrict__ bn_b, float* __restrict__ bnp) {
  const int n = blockIdx.x;
  __shared__ float rs[256], rq[256];
  const int tid = threadIdx.x;
  float s = 0.f, sq = 0.f;
  for (int r = tid; r < NB; r += 256) {
    const float v = zmat[r * NC + n];
    s += v;
    sq += v * v;
  }
  rs[tid] = s; rq[tid] = sq;
  __syncthreads();
  for (int st = 128; st > 0; st >>= 1) {
    if (tid < st) { rs[tid] += rs[tid + st]; rq[tid] += rq[tid + st]; }
    __syncthreads();
  }
  if (tid == 0) {
    const float mean = rs[0] * (1.f / NB);
    const float var = rq[0] * (1.f / NB) - mean * mean;
    const float sc = bn_g[n] * rsqrtf(var + 1e-5f);
    bnp[2 * n] = sc;
    bnp[2 * n + 1] = bn_b[n] - mean * sc;
  }
}

// =====================================================================
// Kernel D2: BN + sigmoid -> output1; 62->2 FC -> output (unchanged).
// =====================================================================
__global__ __launch_bounds__(64) void k_bn_out(
    const float* __restrict__ zmat, const float* __restrict__ bnp,
    const float* __restrict__ fc4_w, const float* __restrict__ fc4_b,
    float* __restrict__ out) {
  const int b = blockIdx.x;
  const int lane = threadIdx.x;
  float o1 = 0.f;
  if (lane < NC) {
    float z = zmat[b * NC + lane];
    z = z * bnp[2 * lane] + bnp[2 * lane + 1];
    o1 = 1.f / (1.f + __expf(-z));
    out[b * NC + lane] = o1;
  }
  float p0 = (lane < NC) ? o1 * fc4_w[lane] : 0.f;
  float p1 = (lane < NC) ? o1 * fc4_w[NC + lane] : 0.f;
#pragma unroll
  for (int off = 32; off > 0; off >>= 1) {
    p0 += __shfl_down(p0, off, 64);
    p1 += __shfl_down(p1, off, 64);
  }
  if (lane == 0) {
    out[NB * NC + b * 2 + 0] = p0 + fc4_b[0];
    out[NB * NC + b * 2 + 1] = p1 + fc4_b[1];
  }
}

extern "C" void kernel_launch(void* const* d_in, const int* in_sizes, int n_in,
                              void* d_out, int out_size, void* d_ws, size_t ws_size,
                              hipStream_t stream) {
  const float* de      = (const float*)d_in[0];
  const float* pcc     = (const float*)d_in[1];
  const float* Aadj    = (const float*)d_in[2];
  // d_in[3] conv_w, d_in[4] conv_b: dead (gate cancels in trace-normalized SPD)
  const float* hconv_w = (const float*)d_in[5];
  const float* hconv_b = (const float*)d_in[6];
  const float* hlin_w  = (const float*)d_in[7];
  const float* hlin_b  = (const float*)d_in[8];
  const float* econv_w = (const float*)d_in[9];
  const float* econv_b = (const float*)d_in[10];
  const float* elin_w  = (const float*)d_in[11];
  const float* elin_b  = (const float*)d_in[12];
  const float* att_w1  = (const float*)d_in[13];
  const float* att_b1  = (const float*)d_in[14];
  const float* att_w2  = (const float*)d_in[15];
  const float* gc_w    = (const float*)d_in[16];
  const float* gc_b    = (const float*)d_in[17];
  // d_in[18] wpar: wnorm = exp(w)/exp(w) = 1 exactly for 1-element wpar
  const float* fc_w    = (const float*)d_in[19];
  const float* fc_b    = (const float*)d_in[20];
  const float* bn_g    = (const float*)d_in[21];
  const float* bn_b    = (const float*)d_in[22];
  const float* fc4_w   = (const float*)d_in[23];
  const float* fc4_b   = (const float*)d_in[24];

  float* ws        = (float*)d_ws;
  _Float16* comH   = (_Float16*)ws;                      // 5120*4096 halves = 41.9 MB
  float* hidden    = ws + 10485760;                      //  3,936,256 floats
  float* essential = hidden + (size_t)NB * NC * NC;
  float* zmat      = essential + (size_t)NB * NC * NC;   //     63,488
  float* bnp       = zmat + (size_t)NB * NC;             //        128
  unsigned int* lwHg = (unsigned int*)(bnp + 128);       //      4,096 u32 (2 x 64 x 32)
  unsigned int* w1Hg = lwHg + 4096;                      //        320 u32
  float* rsumG     = (float*)(w1Hg + 512);               //        128
  // total ~74 MB of workspace

  k_spd<<<NB * NBAND, 256, 0, stream>>>(pcc, Aadj, hlin_w, elin_w, att_w1,
                                        comH, lwHg, w1Hg, rsumG);
  k_branch<<<NB * 2, 256, 0, stream>>>(comH, lwHg, w1Hg, rsumG,
      hconv_w, hconv_b, hlin_b,
      econv_w, econv_b, elin_b,
      att_b1, att_w2, hidden, essential);
  k_cheb_fc<<<NB, 256, 0, stream>>>(de, hidden, essential, gc_w, gc_b, fc_w, fc_b, zmat);
  k_bnstats<<<NC, 256, 0, stream>>>(zmat, bn_g, bn_b, bnp);
  k_bn_out<<<NB, 64, 0, stream>>>(zmat, bnp, fc4_w, fc4_b, (float*)d_out);
}

// Round 15
// 168.368 us; speedup vs baseline: 1.1062x; 1.1062x over previous
//
#include <hip/hip_runtime.h>
#include <math.h>

#define NB    1024
#define NC    62
#define NBAND 5
#define NOUT  16
#define NHID  10
#define ZSTR  68   // zS row stride in f16
#define XTW   34   // XcT row stride in u32 (64 f16 + pad)

typedef __attribute__((ext_vector_type(2))) float f32x2;
typedef __attribute__((ext_vector_type(4))) float f32x4;
typedef __attribute__((ext_vector_type(2))) _Float16 f16x2;
typedef __attribute__((ext_vector_type(8))) _Float16 f16x8;
typedef __attribute__((ext_vector_type(2))) __fp16 fp16v2;   // cvt_pkrtz result type
#define FMA2(a, b, c) __builtin_elementwise_fma((a), (b), (c))
#define DOT2(a, b, c) __builtin_amdgcn_fdot2((a), (b), (c), false)

__device__ __forceinline__ f16x2 u2h(unsigned int u) { return __builtin_bit_cast(f16x2, u); }
__device__ __forceinline__ unsigned int pk2u(float x, float y) {
  const fp16v2 v = __builtin_amdgcn_cvt_pkrtz(x, y);
  return __builtin_bit_cast(unsigned int, v);
}

// =====================================================================
// Kernel A (v14, band-fused): ONE block per b computes all 5 bands.
// Phase A: pcc[b] read ONCE as dense float4 (every element used),
// relu+f16 scatter -> pH[k][i][j] (39.7 KB). Band loop: gather pH[k],
// center, scaled-pack to XcT, MFMA SYRK (v12-validated recipe) for
// src0; Aadj band k read coalesced per band (reg-prefetch at band
// start), same pipeline for src1; store com band k.
// =====================================================================
__global__ __launch_bounds__(256) void k_spd(
    const float* __restrict__ pcc, const float* __restrict__ Aadj,
    const float* __restrict__ hlin_w, const float* __restrict__ elin_w,
    const float* __restrict__ att_w1,
    _Float16* __restrict__ comH, unsigned int* __restrict__ lwHg,
    unsigned int* __restrict__ w1Hg, float* __restrict__ rsumG) {
  const int b = (blockIdx.x & 7) * 128 + (blockIdx.x >> 3);  // XCD swizzle, 1024%8==0
  __shared__ __align__(16) _Float16 pH[NBAND * NC * 64];   // 39,680 B  [k][i][j]
  __shared__ __align__(16) unsigned int XcT[64 * XTW];     //  8,704 B  f16 [c][i]
  __shared__ float red4a[4], red4b[4];
  const int tid = threadIdx.x;
  const int wave = tid >> 6, lane = tid & 63;
  const int p = tid >> 3, q8 = tid & 7, c0 = q8 * 8;
  const bool act = (p < 31);
  const int r0 = 2 * p, r1 = r0 + 1;
  const int mrow = lane & 15, g = lane >> 4;

  float ld0[8], ld1[8];   // pcc band centered values
  float lA0[8], lA1[8];   // Aadj band prefetch / centered values

  auto center = [&](float (&a0)[8], float (&a1)[8], float* red) -> void {
    float s0 = 0.f, s1 = 0.f;
#pragma unroll
    for (int u = 0; u < 8; ++u) { s0 += a0[u]; s1 += a1[u]; }
    s0 += __shfl_xor(s0, 1, 64); s0 += __shfl_xor(s0, 2, 64); s0 += __shfl_xor(s0, 4, 64);
    s1 += __shfl_xor(s1, 1, 64); s1 += __shfl_xor(s1, 2, 64); s1 += __shfl_xor(s1, 4, 64);
    const float m0 = s0 * (1.f / NC), m1 = s1 * (1.f / NC);
    float sq = 0.f;
#pragma unroll
    for (int u = 0; u < 8; ++u) {
      const bool in = act && (c0 + u < NC);
      const float cv0 = in ? (a0[u] - m0) : 0.f;
      const float cv1 = in ? (a1[u] - m1) : 0.f;
      a0[u] = cv0;
      a1[u] = cv1;
      sq += cv0 * cv0 + cv1 * cv1;
    }
#pragma unroll
    for (int off = 1; off < 64; off <<= 1) sq += __shfl_xor(sq, off, 64);
    if (lane == 0) red[wave] = sq;
  };

  auto xct_write = [&](const float (&a0)[8], const float (&a1)[8], float sc) -> void {
#pragma unroll
    for (int u = 0; u < 8; ++u)
      XcT[(c0 + u) * XTW + p] = pk2u(sc * a0[u], sc * a1[u]);
  };

  auto fragread = [&](int row, int s) -> f16x8 {
    const unsigned int* pp = &XcT[row * XTW + 16 * s + 4 * g];
    const uint2 a = *reinterpret_cast<const uint2*>(pp);
    const uint2 b2 = *reinterpret_cast<const uint2*>(pp + 2);
    const uint4 v = make_uint4(a.x, a.y, b2.x, b2.y);
    return __builtin_bit_cast(f16x8, v);
  };

  // ---- Phase A: dense pcc[b] read, relu, scatter ALL elements to pH
  {
    const float4* src = reinterpret_cast<const float4*>(pcc + (size_t)b * (NC * NC * NBAND));
#pragma unroll
    for (int it = 0; it < 19; ++it) {
      const int fidx = tid + it * 256;
      if (fidx < 4805) {                       // 19220 floats / 4 exactly
        const float4 v = src[fidx];
        const int g0 = 4 * fidx;
        int i = g0 / 310;
        int rem = g0 - i * 310;
        int j = rem / 5;
        int k = rem - j * 5;
        const float vals[4] = {v.x, v.y, v.z, v.w};
#pragma unroll
        for (int e = 0; e < 4; ++e) {
          pH[k * (NC * 64) + i * 64 + j] = (_Float16)fmaxf(vals[e], 0.f);
          if (++k == 5) { k = 0; if (++j == NC) { j = 0; ++i; } }
        }
      }
    }
  }
  __syncthreads();   // pH ready

  // ---- band loop
#pragma unroll 1
  for (int kb = 0; kb < NBAND; ++kb) {
    const int bk = b * NBAND + kb;

    // issue Aadj band kb loads (coalesced float2; land by src1 phase)
#pragma unroll
    for (int u = 0; u < 8; ++u) { lA0[u] = 0.f; lA1[u] = 0.f; }
    if (act) {
      const float* a0p = Aadj + ((size_t)bk * NC + r0) * NC + c0;
      const float* a1p = Aadj + ((size_t)bk * NC + r1) * NC + c0;
#pragma unroll
      for (int e = 0; e < 4; ++e) {
        const int c = c0 + 2 * e;
        if (c + 1 < NC) {
          const float2 v0 = *reinterpret_cast<const float2*>(a0p + 2 * e);
          const float2 v1 = *reinterpret_cast<const float2*>(a1p + 2 * e);
          lA0[2 * e] = v0.x; lA0[2 * e + 1] = v0.y;
          lA1[2 * e] = v1.x; lA1[2 * e + 1] = v1.y;
        } else if (c < NC) {
          lA0[2 * e] = a0p[2 * e];
          lA1[2 * e] = a1p[2 * e];
        }
      }
    }

    // gather pH band kb rows (relu already applied)
#pragma unroll
    for (int u = 0; u < 8; ++u) { ld0[u] = 0.f; ld1[u] = 0.f; }
    if (act) {
      const _Float16* ph = pH + kb * (NC * 64);
#pragma unroll
      for (int u = 0; u < 8; ++u) {
        const int c = c0 + u;
        if (c < NC) {
          ld0[u] = (float)ph[r0 * 64 + c];
          ld1[u] = (float)ph[r1 * 64 + c];
        }
      }
    }
    center(ld0, ld1, red4a);
    __syncthreads();   // (1) red4a ready; prev band's MFMA XcT reads done

    const float tra0 = red4a[0] + red4a[1] + red4a[2] + red4a[3];
    xct_write(ld0, ld1, sqrtf(0.5f / tra0));
    __syncthreads();   // (2) XcT(src0) ready

    f32x4 acc[4];
#pragma unroll
    for (int n = 0; n < 4; ++n) acc[n] = (f32x4){0.f, 0.f, 0.f, 0.f};
    {
      const f16x8 A0 = fragread(16 * wave + mrow, 0);
      const f16x8 A1 = fragread(16 * wave + mrow, 1);
#pragma unroll
      for (int n = 0; n < 4; ++n) {
        const f16x8 B0 = fragread(16 * n + mrow, 0);
        const f16x8 B1 = fragread(16 * n + mrow, 1);
        acc[n] = __builtin_amdgcn_mfma_f32_16x16x32_f16(A0, B0, acc[n], 0, 0, 0);
        acc[n] = __builtin_amdgcn_mfma_f32_16x16x32_f16(A1, B1, acc[n], 0, 0, 0);
      }
    }

    // src1 = Aadj band: relu + center (VALU overlaps MFMA)
#pragma unroll
    for (int u = 0; u < 8; ++u) { lA0[u] = fmaxf(lA0[u], 0.f); lA1[u] = fmaxf(lA1[u], 0.f); }
    center(lA0, lA1, red4b);
    __syncthreads();   // (3) red4b ready; MFMA src0 XcT reads done

    const float tra1 = red4b[0] + red4b[1] + red4b[2] + red4b[3];
    xct_write(lA0, lA1, sqrtf(0.5f / tra1));
    __syncthreads();   // (4) XcT(src1) ready

    {
      const f16x8 A0 = fragread(16 * wave + mrow, 0);
      const f16x8 A1 = fragread(16 * wave + mrow, 1);
#pragma unroll
      for (int n = 0; n < 4; ++n) {
        const f16x8 B0 = fragread(16 * n + mrow, 0);
        const f16x8 B1 = fragread(16 * n + mrow, 1);
        acc[n] = __builtin_amdgcn_mfma_f32_16x16x32_f16(A0, B0, acc[n], 0, 0, 0);
        acc[n] = __builtin_amdgcn_mfma_f32_16x16x32_f16(A1, B1, acc[n], 0, 0, 0);
      }
    }

    // epilogue: diag + f16 store. r = 16*wave+4g+reg, col = 16n+mrow.
#pragma unroll
    for (int reg = 0; reg < 4; ++reg) {
      const int r = 16 * wave + 4 * g + reg;
#pragma unroll
      for (int n = 0; n < 4; ++n) {
        float v = acc[n][reg];
        if (n == wave && mrow == 4 * g + reg) v += 1e-5f;   // diagonal
        comH[(size_t)bk * 4096 + r * 64 + 16 * n + mrow] = (_Float16)v;
      }
    }
  }

  // ---- block 0 epilogue: lwHg row-major f16 [br][o][c], w1H, row sums
  if (blockIdx.x == 0) {
    for (int t = tid; t < 2 * 64 * 32; t += 256) {
      const int brx = t >> 11, rem = t & 2047, o = rem >> 5, cp = rem & 31;
      const float* lwsrc = brx ? elin_w : hlin_w;
      float lo = 0.f, hi = 0.f;
      if (o < NC) {
        const int c = 2 * cp;
        if (c < NC)     lo = lwsrc[o * NC + c];
        if (c + 1 < NC) hi = lwsrc[o * NC + c + 1];
      }
      lwHg[t] = pk2u(lo, hi);   // [br][o][c-pair] row-major
    }
    for (int t = tid; t < NHID * 32; t += 256) {
      const int h = t >> 5, op = t & 31;
      const float lo = (2 * op < NC) ? att_w1[h * NC + 2 * op] : 0.f;
      const float hi = (2 * op + 1 < NC) ? att_w1[h * NC + 2 * op + 1] : 0.f;
      w1Hg[t] = pk2u(lo, hi);
    }
    if (tid < 64) {
      float sh = 0.f, se = 0.f;
      if (tid < NC) {
        for (int c = 0; c < NC; ++c) { sh += hlin_w[tid * NC + c]; se += elin_w[tid * NC + c]; }
      }
      rsumG[tid] = sh;
      rsumG[64 + tid] = se;
    }
  }
}

// =====================================================================
// Kernel B (v11, MFMA): unchanged (validated).
// =====================================================================
__global__ __launch_bounds__(256, 2) void k_branch(
    const _Float16* __restrict__ comH, const unsigned int* __restrict__ lwHg,
    const unsigned int* __restrict__ w1Hg, const float* __restrict__ rsumG,
    const float* __restrict__ hconv_w, const float* __restrict__ hconv_b,
    const float* __restrict__ hlin_b,
    const float* __restrict__ econv_w, const float* __restrict__ econv_b,
    const float* __restrict__ elin_b,
    const float* __restrict__ att_b1,  const float* __restrict__ att_w2,
    float* __restrict__ hiddenO, float* __restrict__ essentialO) {
  const int bid = (blockIdx.x & 7) * 256 + (blockIdx.x >> 3);  // XCD swizzle
  const int b = bid >> 1, br = bid & 1;

  const float* __restrict__ cw = br ? econv_w : hconv_w;
  const float* __restrict__ cb = br ? econv_b : hconv_b;
  const float* __restrict__ lb = br ? elin_b : hlin_b;
  float* __restrict__ outp = br ? essentialO : hiddenO;

  __shared__ __align__(16) unsigned int comS[64 * 32];     // 8 KB, XOR-swizzled
  __shared__ __align__(16) _Float16 zS[4][16 * ZSTR];      // 8.7 KB, per-wave
  __shared__ __align__(16) unsigned int w1S[NHID * 32];    // o-pair f16
  __shared__ float scoreS[4][16];
  __shared__ float b1S[16], w2S[16], cwS[8], cbS[8];

  const int tid = threadIdx.x;
  const int w = tid >> 6, lane = tid & 63;
  const int mrow = lane & 15;       // A-row within strip / C col-within-tile
  const int g = lane >> 4;          // k-group / C row-group

  // ---- param fills (block-wide -> one barrier)
  for (int t = tid; t < NHID * 32; t += 256) w1S[t] = w1Hg[t];
  if (tid < NHID) { b1S[tid] = att_b1[tid]; w2S[tid] = att_w2[tid]; }
  if (tid < NBAND) { cwS[tid] = cw[tid]; cbS[tid] = cb[tid]; }

  // ---- B-frags in registers (band-invariant): B[s][n], col = 16n+mrow
  f16x8 Bf[2][4];
  float rsumR[4], lbR[4];
#pragma unroll
  for (int n = 0; n < 4; ++n) {
    const int col = 16 * n + mrow;
    rsumR[n] = rsumG[br * 64 + col];
    lbR[n] = (col < NC) ? lb[col] : 0.f;
#pragma unroll
    for (int s = 0; s < 2; ++s) {
      const uint4 v = *reinterpret_cast<const uint4*>(lwHg + br * 2048 + col * 32 + s * 16 + g * 4);
      Bf[s][n] = __builtin_bit_cast(f16x8, v);
    }
  }
  __syncthreads();   // w1S/b1S/w2S/cwS/cbS visible to all waves

  // ---- staging: wave w stages ITS strip rows 16w..16w+15 (128 uint4).
  const uint4* gsrc = reinterpret_cast<const uint4*>(comH + (size_t)(b * NBAND) * 4096);
  uint4 pf[2];
  auto stage_issue = [&](int band) {
#pragma unroll
    for (int i = 0; i < 2; ++i) pf[i] = gsrc[band * 512 + w * 128 + i * 64 + lane];
  };
  auto stage_write = [&]() {
#pragma unroll
    for (int i = 0; i < 2; ++i) {
      const int idx = i * 64 + lane;          // within strip: 0..127
      const int row = 16 * w + (idx >> 3), slot = idx & 7;
      const int sb = (slot * 16) ^ ((row & 7) << 4);   // swizzled byte in row
      *reinterpret_cast<uint4*>(comS + row * 32 + sb / 4) = pf[i];
    }
  };

  auto a_frag = [&](int s) -> f16x8 {
    const int row = 16 * w + mrow;
    const int sb = (64 * s + 16 * g) ^ ((row & 7) << 4);
    return __builtin_bit_cast(f16x8, *reinterpret_cast<const uint4*>(comS + row * 32 + sb / 4));
  };

  stage_issue(0);
  stage_write();

  f32x4 oacc[4];
#pragma unroll
  for (int n = 0; n < 4; ++n) oacc[n] = (f32x4){0.f, 0.f, 0.f, 0.f};
  float denom[4] = {0.f, 0.f, 0.f, 0.f};
  float mrun[4] = {-1e30f, -1e30f, -1e30f, -1e30f};

  _Float16* zSw = &zS[w][0];   // wave-private
  const int rowz = lane >> 2, qz = lane & 3;   // scorer mapping

#pragma unroll 1
  for (int kb = 0; kb < NBAND; ++kb) {
    if (kb < NBAND - 1) stage_issue(kb + 1);   // T14: issue early

    // ---- MFMA GEMM: acc[n] = A(strip) x B[n], K=64 in 2 steps
    const f16x8 A0 = a_frag(0);
    const f16x8 A1 = a_frag(1);
    f32x4 acc[4];
#pragma unroll
    for (int n = 0; n < 4; ++n) {
      acc[n] = __builtin_amdgcn_mfma_f32_16x16x32_f16(A0, Bf[0][n], (f32x4){0.f, 0.f, 0.f, 0.f}, 0, 0, 0);
      acc[n] = __builtin_amdgcn_mfma_f32_16x16x32_f16(A1, Bf[1][n], acc[n], 0, 0, 0);
    }

    if (kb < NBAND - 1) stage_write();   // in-order DS: lands after A reads

    // ---- sigmoid in C-layout regs; write z to wave-private zS (f16)
    const float ck = cwS[kb], dk = cbS[kb];
#pragma unroll
    for (int n = 0; n < 4; ++n) {
      const float base = dk * rsumR[n] + lbR[n];
#pragma unroll
      for (int reg = 0; reg < 4; ++reg) {
        const float zv = 1.f / (1.f + __expf(-(ck * acc[n][reg] + base)));
        acc[n][reg] = zv;
        zSw[(4 * g + reg) * ZSTR + 16 * n + mrow] = (_Float16)zv;
      }
    }

    // ---- scorer over zS rows: row = lane>>2, q = lane&3
    {
      const _Float16* zr = zSw + rowz * ZSTR + qz * 16;
      unsigned int zh[8];
#pragma unroll
      for (int j = 0; j < 4; ++j) {
        const uint2 v = *reinterpret_cast<const uint2*>(zr + 4 * j);  // 8B-aligned
        zh[2 * j] = v.x;
        zh[2 * j + 1] = v.y;
      }
      float sacc = 0.f;
#pragma unroll
      for (int t = 0; t < 5; ++t) {
        const int hA = 2 * t, hB = 2 * t + 1;
        const uint4 wa0 = *reinterpret_cast<const uint4*>(w1S + hA * 32 + qz * 8);
        const uint4 wa1 = *reinterpret_cast<const uint4*>(w1S + hA * 32 + qz * 8 + 4);
        const uint4 wb0 = *reinterpret_cast<const uint4*>(w1S + hB * 32 + qz * 8);
        const uint4 wb1 = *reinterpret_cast<const uint4*>(w1S + hB * 32 + qz * 8 + 4);
        const unsigned int wau[8] = {wa0.x, wa0.y, wa0.z, wa0.w, wa1.x, wa1.y, wa1.z, wa1.w};
        const unsigned int wbu[8] = {wb0.x, wb0.y, wb0.z, wb0.w, wb1.x, wb1.y, wb1.z, wb1.w};
        float pA = 0.f, pB = 0.f;
#pragma unroll
        for (int u = 0; u < 8; ++u) {
          pA = DOT2(u2h(zh[u]), u2h(wau[u]), pA);
          pB = DOT2(u2h(zh[u]), u2h(wbu[u]), pB);
        }
        pA += __shfl_xor(pA, 1, 64); pA += __shfl_xor(pA, 2, 64);
        pB += __shfl_xor(pB, 1, 64); pB += __shfl_xor(pB, 2, 64);
        const float exA = __expf(2.f * (pA + b1S[hA]));
        const float exB = __expf(2.f * (pB + b1S[hB]));
        sacc += w2S[hA] * (1.f - 2.f / (exA + 1.f));
        sacc += w2S[hB] * (1.f - 2.f / (exB + 1.f));
      }
      if (qz == 0) scoreS[w][rowz] = sacc;
    }

    // ---- online softmax on C-layout accs (rows 4g+reg)
#pragma unroll
    for (int reg = 0; reg < 4; ++reg) {
      const float sc = scoreS[w][4 * g + reg];     // in-order after write
      const float nm = fmaxf(mrun[reg], sc);
      const float f = __expf(mrun[reg] - nm), e = __expf(sc - nm);
      denom[reg] = denom[reg] * f + e;
#pragma unroll
      for (int n = 0; n < 4; ++n)
        oacc[n][reg] = oacc[n][reg] * f + e * acc[n][reg];
      mrun[reg] = nm;
    }
  }

  // ---- store: r = 16w + 4g + reg, col = 16n + mrow
#pragma unroll
  for (int reg = 0; reg < 4; ++reg) {
    const int r = 16 * w + 4 * g + reg;
    if (r < NC) {
      const float inv = 1.f / denom[reg];
#pragma unroll
      for (int n = 0; n < 4; ++n) {
        const int col = 16 * n + mrow;
        if (col < NC) outp[(size_t)b * (NC * NC) + r * NC + col] = oacc[n][reg] * inv;
      }
    }
  }
}

// =====================================================================
// Kernel C: Chebyshev GCN + feature + 992->62 FC (unchanged).
// =====================================================================
__global__ __launch_bounds__(256) void k_cheb_fc(
    const float* __restrict__ de, const float* __restrict__ hidden,
    const float* __restrict__ essential, const float* __restrict__ gc_w,
    const float* __restrict__ gc_b, const float* __restrict__ fc_w,
    const float* __restrict__ fc_b, float* __restrict__ zmat) {
  const int b = blockIdx.x;
  __shared__ float hidS[NC * NC], essS[NC * NC];
  __shared__ float t0S[NC * NOUT], t1S[NC * NOUT];
  __shared__ float featS[NC * NOUT];
  __shared__ float deS[NC * NBAND];
  __shared__ float red2[256];
  const int tid = threadIdx.x;

  for (int t = tid; t < NC * NBAND; t += 256) deS[t] = de[b * NC * NBAND + t];
  for (int t = tid; t < NC * NC; t += 256) {
    hidS[t] = hidden[b * NC * NC + t];
    essS[t] = essential[b * NC * NC + t];
  }
  __syncthreads();
  for (int t = tid; t < NC * NOUT; t += 256) {
    const int i = t / NOUT, f = t % NOUT;
    float a0 = gc_b[f];
    float a1 = 0.f;
#pragma unroll
    for (int qq = 0; qq < NBAND; ++qq) {
      const float d = deS[i * NBAND + qq];
      a0 += d * gc_w[qq * NOUT + f];
      a1 += d * gc_w[(NBAND + qq) * NOUT + f];
    }
    t0S[t] = a0;
    t1S[t] = a1;
  }
  __syncthreads();
  for (int t = tid; t < NC * NOUT; t += 256) {
    const int i = t / NOUT, f = t % NOUT;
    float sh = 0.f, se = 0.f;
    for (int jj = 0; jj < NC; ++jj) {
      const float t1 = t1S[jj * NOUT + f];
      sh += hidS[i * NC + jj] * t1;
      se += essS[i * NC + jj] * t1;
    }
    const float gb1 = gc_b[NOUT + f];
    const float h = fmaxf(t0S[t] + sh + gb1, 0.f);
    const float e = fmaxf(t0S[t] + se + gb1, 0.f);
    featS[t] = 0.5f * (h + e);
  }
  __syncthreads();
  {
    const int n = tid >> 2, qq = tid & 3;
    float p = 0.f;
    if (n < NC) {
      const float* fw = fc_w + n * (NC * NOUT) + qq * 248;
      const float* fs = featS + qq * 248;
      for (int m = 0; m < 248; ++m) p += fs[m] * fw[m];
    }
    red2[tid] = p;
    __syncthreads();
    if (tid < NC) {
      const float z = red2[tid * 4] + red2[tid * 4 + 1] + red2[tid * 4 + 2] + red2[tid * 4 + 3] + fc_b[tid];
      zmat[b * NC + tid] = z;
    }
  }
}

// =====================================================================
// Kernel D1: batch-norm statistics (unchanged).
// =====================================================================
__global__ __launch_bounds__(256) void k_bnstats(
    const float* __restrict__ zmat, const float* __restrict__ bn_g,
    const float* __restrict__ bn_b, float* __restrict__ bnp) {
  const int n = blockIdx.x;
  __shared__ float rs[256], rq[256];
  const int tid = threadIdx.x;
  float s = 0.f, sq = 0.f;
  for (int r = tid; r < NB; r += 256) {
    const float v = zmat[r * NC + n];
    s += v;
    sq += v * v;
  }
  rs[tid] = s; rq[tid] = sq;
  __syncthreads();
  for (int st = 128; st > 0; st >>= 1) {
    if (tid < st) { rs[tid] += rs[tid + st]; rq[tid] += rq[tid + st]; }
    __syncthreads();
  }
  if (tid == 0) {
    const float mean = rs[0] * (1.f / NB);
    const float var = rq[0] * (1.f / NB) - mean * mean;
    const float sc = bn_g[n] * rsqrtf(var + 1e-5f);
    bnp[2 * n] = sc;
    bnp[2 * n + 1] = bn_b[n] - mean * sc;
  }
}

// =====================================================================
// Kernel D2: BN + sigmoid -> output1; 62->2 FC -> output (unchanged).
// =====================================================================
__global__ __launch_bounds__(64) void k_bn_out(
    const float* __restrict__ zmat, const float* __restrict__ bnp,
    const float* __restrict__ fc4_w, const float* __restrict__ fc4_b,
    float* __restrict__ out) {
  const int b = blockIdx.x;
  const int lane = threadIdx.x;
  float o1 = 0.f;
  if (lane < NC) {
    float z = zmat[b * NC + lane];
    z = z * bnp[2 * lane] + bnp[2 * lane + 1];
    o1 = 1.f / (1.f + __expf(-z));
    out[b * NC + lane] = o1;
  }
  float p0 = (lane < NC) ? o1 * fc4_w[lane] : 0.f;
  float p1 = (lane < NC) ? o1 * fc4_w[NC + lane] : 0.f;
#pragma unroll
  for (int off = 32; off > 0; off >>= 1) {
    p0 += __shfl_down(p0, off, 64);
    p1 += __shfl_down(p1, off, 64);
  }
  if (lane == 0) {
    out[NB * NC + b * 2 + 0] = p0 + fc4_b[0];
    out[NB * NC + b * 2 + 1] = p1 + fc4_b[1];
  }
}

extern "C" void kernel_launch(void* const* d_in, const int* in_sizes, int n_in,
                              void* d_out, int out_size, void* d_ws, size_t ws_size,
                              hipStream_t stream) {
  const float* de      = (const float*)d_in[0];
  const float* pcc     = (const float*)d_in[1];
  const float* Aadj    = (const float*)d_in[2];
  // d_in[3] conv_w, d_in[4] conv_b: dead (gate cancels in trace-normalized SPD)
  const float* hconv_w = (const float*)d_in[5];
  const float* hconv_b = (const float*)d_in[6];
  const float* hlin_w  = (const float*)d_in[7];
  const float* hlin_b  = (const float*)d_in[8];
  const float* econv_w = (const float*)d_in[9];
  const float* econv_b = (const float*)d_in[10];
  const float* elin_w  = (const float*)d_in[11];
  const float* elin_b  = (const float*)d_in[12];
  const float* att_w1  = (const float*)d_in[13];
  const float* att_b1  = (const float*)d_in[14];
  const float* att_w2  = (const float*)d_in[15];
  const float* gc_w    = (const float*)d_in[16];
  const float* gc_b    = (const float*)d_in[17];
  // d_in[18] wpar: wnorm = exp(w)/exp(w) = 1 exactly for 1-element wpar
  const float* fc_w    = (const float*)d_in[19];
  const float* fc_b    = (const float*)d_in[20];
  const float* bn_g    = (const float*)d_in[21];
  const float* bn_b    = (const float*)d_in[22];
  const float* fc4_w   = (const float*)d_in[23];
  const float* fc4_b   = (const float*)d_in[24];

  float* ws        = (float*)d_ws;
  _Float16* comH   = (_Float16*)ws;                      // 5120*4096 halves = 41.9 MB
  float* hidden    = ws + 10485760;                      //  3,936,256 floats
  float* essential = hidden + (size_t)NB * NC * NC;
  float* zmat      = essential + (size_t)NB * NC * NC;   //     63,488
  float* bnp       = zmat + (size_t)NB * NC;             //        128
  unsigned int* lwHg = (unsigned int*)(bnp + 128);       //      4,096 u32 (2 x 64 x 32)
  unsigned int* w1Hg = lwHg + 4096;                      //        320 u32
  float* rsumG     = (float*)(w1Hg + 512);               //        128
  // total ~74 MB of workspace

  k_spd<<<NB, 256, 0, stream>>>(pcc, Aadj, hlin_w, elin_w, att_w1,
                                comH, lwHg, w1Hg, rsumG);
  k_branch<<<NB * 2, 256, 0, stream>>>(comH, lwHg, w1Hg, rsumG,
      hconv_w, hconv_b, hlin_b,
      econv_w, econv_b, elin_b,
      att_b1, att_w2, hidden, essential);
  k_cheb_fc<<<NB, 256, 0, stream>>>(de, hidden, essential, gc_w, gc_b, fc_w, fc_b, zmat);
  k_bnstats<<<NC, 256, 0, stream>>>(zmat, bn_g, bn_b, bnp);
  k_bn_out<<<NB, 64, 0, stream>>>(zmat, bnp, fc4_w, fc4_b, (float*)d_out);
}

// Round 16
// 148.074 us; speedup vs baseline: 1.2579x; 1.1371x over previous
//
#include <hip/hip_runtime.h>
#include <math.h>

#define NB    1024
#define NC    62
#define NBAND 5
#define NOUT  16
#define NHID  10
#define ZSTR  72   // zS row stride in f16 (144B: 16B-aligned rows, free 2-way banks)
#define XTW   34   // XcT row stride in u32 (64 f16 + pad)

typedef __attribute__((ext_vector_type(2))) float f32x2;
typedef __attribute__((ext_vector_type(4))) float f32x4;
typedef __attribute__((ext_vector_type(2))) _Float16 f16x2;
typedef __attribute__((ext_vector_type(8))) _Float16 f16x8;
typedef __attribute__((ext_vector_type(2))) __fp16 fp16v2;   // cvt_pkrtz result type
#define FMA2(a, b, c) __builtin_elementwise_fma((a), (b), (c))
#define DOT2(a, b, c) __builtin_amdgcn_fdot2((a), (b), (c), false)

__device__ __forceinline__ f16x2 u2h(unsigned int u) { return __builtin_bit_cast(f16x2, u); }
__device__ __forceinline__ unsigned int pk2u(float x, float y) {
  const fp16v2 v = __builtin_amdgcn_cvt_pkrtz(x, y);
  return __builtin_bit_cast(unsigned int, v);
}

// =====================================================================
// Kernel A (v14, band-fused): ONE block per b computes all 5 bands.
// Phase A: pcc[b] read ONCE as dense float4, relu+f16 scatter ->
// pH[k][i][j]. Band loop: gather pH[k], center, scaled-pack to XcT,
// MFMA SYRK (validated recipe); Aadj band coalesced + reg-prefetched.
// Epilogue (block 0): lwHg row-major f16, w1Hg padded to 16 rows, rsums.
// =====================================================================
__global__ __launch_bounds__(256) void k_spd(
    const float* __restrict__ pcc, const float* __restrict__ Aadj,
    const float* __restrict__ hlin_w, const float* __restrict__ elin_w,
    const float* __restrict__ att_w1,
    _Float16* __restrict__ comH, unsigned int* __restrict__ lwHg,
    unsigned int* __restrict__ w1Hg, float* __restrict__ rsumG) {
  const int b = (blockIdx.x & 7) * 128 + (blockIdx.x >> 3);  // XCD swizzle, 1024%8==0
  __shared__ __align__(16) _Float16 pH[NBAND * NC * 64];   // 39,680 B  [k][i][j]
  __shared__ __align__(16) unsigned int XcT[64 * XTW];     //  8,704 B  f16 [c][i]
  __shared__ float red4a[4], red4b[4];
  const int tid = threadIdx.x;
  const int wave = tid >> 6, lane = tid & 63;
  const int p = tid >> 3, q8 = tid & 7, c0 = q8 * 8;
  const bool act = (p < 31);
  const int r0 = 2 * p, r1 = r0 + 1;
  const int mrow = lane & 15, g = lane >> 4;

  float ld0[8], ld1[8];   // pcc band centered values
  float lA0[8], lA1[8];   // Aadj band prefetch / centered values

  auto center = [&](float (&a0)[8], float (&a1)[8], float* red) -> void {
    float s0 = 0.f, s1 = 0.f;
#pragma unroll
    for (int u = 0; u < 8; ++u) { s0 += a0[u]; s1 += a1[u]; }
    s0 += __shfl_xor(s0, 1, 64); s0 += __shfl_xor(s0, 2, 64); s0 += __shfl_xor(s0, 4, 64);
    s1 += __shfl_xor(s1, 1, 64); s1 += __shfl_xor(s1, 2, 64); s1 += __shfl_xor(s1, 4, 64);
    const float m0 = s0 * (1.f / NC), m1 = s1 * (1.f / NC);
    float sq = 0.f;
#pragma unroll
    for (int u = 0; u < 8; ++u) {
      const bool in = act && (c0 + u < NC);
      const float cv0 = in ? (a0[u] - m0) : 0.f;
      const float cv1 = in ? (a1[u] - m1) : 0.f;
      a0[u] = cv0;
      a1[u] = cv1;
      sq += cv0 * cv0 + cv1 * cv1;
    }
#pragma unroll
    for (int off = 1; off < 64; off <<= 1) sq += __shfl_xor(sq, off, 64);
    if (lane == 0) red[wave] = sq;
  };

  auto xct_write = [&](const float (&a0)[8], const float (&a1)[8], float sc) -> void {
#pragma unroll
    for (int u = 0; u < 8; ++u)
      XcT[(c0 + u) * XTW + p] = pk2u(sc * a0[u], sc * a1[u]);
  };

  auto fragread = [&](int row, int s) -> f16x8 {
    const unsigned int* pp = &XcT[row * XTW + 16 * s + 4 * g];
    const uint2 a = *reinterpret_cast<const uint2*>(pp);
    const uint2 b2 = *reinterpret_cast<const uint2*>(pp + 2);
    const uint4 v = make_uint4(a.x, a.y, b2.x, b2.y);
    return __builtin_bit_cast(f16x8, v);
  };

  // ---- Phase A: dense pcc[b] read, relu, scatter ALL elements to pH
  {
    const float4* src = reinterpret_cast<const float4*>(pcc + (size_t)b * (NC * NC * NBAND));
#pragma unroll
    for (int it = 0; it < 19; ++it) {
      const int fidx = tid + it * 256;
      if (fidx < 4805) {                       // 19220 floats / 4 exactly
        const float4 v = src[fidx];
        const int g0 = 4 * fidx;
        int i = g0 / 310;
        int rem = g0 - i * 310;
        int j = rem / 5;
        int k = rem - j * 5;
        const float vals[4] = {v.x, v.y, v.z, v.w};
#pragma unroll
        for (int e = 0; e < 4; ++e) {
          pH[k * (NC * 64) + i * 64 + j] = (_Float16)fmaxf(vals[e], 0.f);
          if (++k == 5) { k = 0; if (++j == NC) { j = 0; ++i; } }
        }
      }
    }
  }
  __syncthreads();   // pH ready

  // ---- band loop
#pragma unroll 1
  for (int kb = 0; kb < NBAND; ++kb) {
    const int bk = b * NBAND + kb;

    // issue Aadj band kb loads (coalesced float2; land by src1 phase)
#pragma unroll
    for (int u = 0; u < 8; ++u) { lA0[u] = 0.f; lA1[u] = 0.f; }
    if (act) {
      const float* a0p = Aadj + ((size_t)bk * NC + r0) * NC + c0;
      const float* a1p = Aadj + ((size_t)bk * NC + r1) * NC + c0;
#pragma unroll
      for (int e = 0; e < 4; ++e) {
        const int c = c0 + 2 * e;
        if (c + 1 < NC) {
          const float2 v0 = *reinterpret_cast<const float2*>(a0p + 2 * e);
          const float2 v1 = *reinterpret_cast<const float2*>(a1p + 2 * e);
          lA0[2 * e] = v0.x; lA0[2 * e + 1] = v0.y;
          lA1[2 * e] = v1.x; lA1[2 * e + 1] = v1.y;
        } else if (c < NC) {
          lA0[2 * e] = a0p[2 * e];
          lA1[2 * e] = a1p[2 * e];
        }
      }
    }

    // gather pH band kb rows (relu already applied)
#pragma unroll
    for (int u = 0; u < 8; ++u) { ld0[u] = 0.f; ld1[u] = 0.f; }
    if (act) {
      const _Float16* ph = pH + kb * (NC * 64);
#pragma unroll
      for (int u = 0; u < 8; ++u) {
        const int c = c0 + u;
        if (c < NC) {
          ld0[u] = (float)ph[r0 * 64 + c];
          ld1[u] = (float)ph[r1 * 64 + c];
        }
      }
    }
    center(ld0, ld1, red4a);
    __syncthreads();   // (1) red4a ready; prev band's MFMA XcT reads done

    const float tra0 = red4a[0] + red4a[1] + red4a[2] + red4a[3];
    xct_write(ld0, ld1, sqrtf(0.5f / tra0));
    __syncthreads();   // (2) XcT(src0) ready

    f32x4 acc[4];
#pragma unroll
    for (int n = 0; n < 4; ++n) acc[n] = (f32x4){0.f, 0.f, 0.f, 0.f};
    {
      const f16x8 A0 = fragread(16 * wave + mrow, 0);
      const f16x8 A1 = fragread(16 * wave + mrow, 1);
#pragma unroll
      for (int n = 0; n < 4; ++n) {
        const f16x8 B0 = fragread(16 * n + mrow, 0);
        const f16x8 B1 = fragread(16 * n + mrow, 1);
        acc[n] = __builtin_amdgcn_mfma_f32_16x16x32_f16(A0, B0, acc[n], 0, 0, 0);
        acc[n] = __builtin_amdgcn_mfma_f32_16x16x32_f16(A1, B1, acc[n], 0, 0, 0);
      }
    }

    // src1 = Aadj band: relu + center (VALU overlaps MFMA)
#pragma unroll
    for (int u = 0; u < 8; ++u) { lA0[u] = fmaxf(lA0[u], 0.f); lA1[u] = fmaxf(lA1[u], 0.f); }
    center(lA0, lA1, red4b);
    __syncthreads();   // (3) red4b ready; MFMA src0 XcT reads done

    const float tra1 = red4b[0] + red4b[1] + red4b[2] + red4b[3];
    xct_write(lA0, lA1, sqrtf(0.5f / tra1));
    __syncthreads();   // (4) XcT(src1) ready

    {
      const f16x8 A0 = fragread(16 * wave + mrow, 0);
      const f16x8 A1 = fragread(16 * wave + mrow, 1);
#pragma unroll
      for (int n = 0; n < 4; ++n) {
        const f16x8 B0 = fragread(16 * n + mrow, 0);
        const f16x8 B1 = fragread(16 * n + mrow, 1);
        acc[n] = __builtin_amdgcn_mfma_f32_16x16x32_f16(A0, B0, acc[n], 0, 0, 0);
        acc[n] = __builtin_amdgcn_mfma_f32_16x16x32_f16(A1, B1, acc[n], 0, 0, 0);
      }
    }

    // epilogue: diag + f16 store. r = 16*wave+4g+reg, col = 16n+mrow.
#pragma unroll
    for (int reg = 0; reg < 4; ++reg) {
      const int r = 16 * wave + 4 * g + reg;
#pragma unroll
      for (int n = 0; n < 4; ++n) {
        float v = acc[n][reg];
        if (n == wave && mrow == 4 * g + reg) v += 1e-5f;   // diagonal
        comH[(size_t)bk * 4096 + r * 64 + 16 * n + mrow] = (_Float16)v;
      }
    }
  }

  // ---- block 0 epilogue: lwHg row-major f16 [br][o][c], w1Hg (16 rows,
  // zero-padded h>=10) for the MFMA scorer, row sums
  if (blockIdx.x == 0) {
    for (int t = tid; t < 2 * 64 * 32; t += 256) {
      const int brx = t >> 11, rem = t & 2047, o = rem >> 5, cp = rem & 31;
      const float* lwsrc = brx ? elin_w : hlin_w;
      float lo = 0.f, hi = 0.f;
      if (o < NC) {
        const int c = 2 * cp;
        if (c < NC)     lo = lwsrc[o * NC + c];
        if (c + 1 < NC) hi = lwsrc[o * NC + c + 1];
      }
      lwHg[t] = pk2u(lo, hi);   // [br][o][c-pair] row-major
    }
    for (int t = tid; t < 16 * 32; t += 256) {
      const int h = t >> 5, op = t & 31;
      float lo = 0.f, hi = 0.f;
      if (h < NHID) {
        if (2 * op < NC)     lo = att_w1[h * NC + 2 * op];
        if (2 * op + 1 < NC) hi = att_w1[h * NC + 2 * op + 1];
      }
      w1Hg[t] = pk2u(lo, hi);
    }
    if (tid < 64) {
      float sh = 0.f, se = 0.f;
      if (tid < NC) {
        for (int c = 0; c < NC; ++c) { sh += hlin_w[tid * NC + c]; se += elin_w[tid * NC + c]; }
      }
      rsumG[tid] = sh;
      rsumG[64 + tid] = se;
    }
  }
}

// =====================================================================
// Kernel B (v12, double-MFMA): z-GEMM as before; SCORER is now also a
// wave-local 16x16x64 MFMA (A = zS strip, B = w1 row-major frags held
// in registers, h>=10 rows zero). Output p lands C-layout: lane holds
// p[4g+reg][h=mrow] -> 4 tanh + 16-lane shfl row-sum gives score[4g+reg]
// directly in the consuming lane. No w1S/scoreS LDS, no qz remap.
// =====================================================================
__global__ __launch_bounds__(256, 2) void k_branch(
    const _Float16* __restrict__ comH, const unsigned int* __restrict__ lwHg,
    const unsigned int* __restrict__ w1Hg, const float* __restrict__ rsumG,
    const float* __restrict__ hconv_w, const float* __restrict__ hconv_b,
    const float* __restrict__ hlin_b,
    const float* __restrict__ econv_w, const float* __restrict__ econv_b,
    const float* __restrict__ elin_b,
    const float* __restrict__ att_b1,  const float* __restrict__ att_w2,
    float* __restrict__ hiddenO, float* __restrict__ essentialO) {
  const int bid = (blockIdx.x & 7) * 256 + (blockIdx.x >> 3);  // XCD swizzle
  const int b = bid >> 1, br = bid & 1;

  const float* __restrict__ cw = br ? econv_w : hconv_w;
  const float* __restrict__ cb = br ? econv_b : hconv_b;
  const float* __restrict__ lb = br ? elin_b : hlin_b;
  float* __restrict__ outp = br ? essentialO : hiddenO;

  __shared__ __align__(16) unsigned int comS[64 * 32];     // 8 KB, XOR-swizzled
  __shared__ __align__(16) _Float16 zS[4][16 * ZSTR];      // 9.2 KB, per-wave
  __shared__ float cwS[8], cbS[8];

  const int tid = threadIdx.x;
  const int w = tid >> 6, lane = tid & 63;
  const int mrow = lane & 15;       // A-row within strip / C col-within-tile
  const int g = lane >> 4;          // k-group / C row-group

  if (tid < NBAND) { cwS[tid] = cw[tid]; cbS[tid] = cb[tid]; }

  // ---- B-frags in registers: lw (4 col-tiles) + w1 (scorer), col = mrow
  f16x8 Bf[2][4], W1f[2];
  float rsumR[4], lbR[4];
#pragma unroll
  for (int n = 0; n < 4; ++n) {
    const int col = 16 * n + mrow;
    rsumR[n] = rsumG[br * 64 + col];
    lbR[n] = (col < NC) ? lb[col] : 0.f;
#pragma unroll
    for (int s = 0; s < 2; ++s) {
      const uint4 v = *reinterpret_cast<const uint4*>(lwHg + br * 2048 + col * 32 + s * 16 + g * 4);
      Bf[s][n] = __builtin_bit_cast(f16x8, v);
    }
  }
#pragma unroll
  for (int s = 0; s < 2; ++s) {
    const uint4 v = *reinterpret_cast<const uint4*>(w1Hg + mrow * 32 + s * 16 + g * 4);
    W1f[s] = __builtin_bit_cast(f16x8, v);
  }
  const float b1R = (mrow < NHID) ? att_b1[mrow] : 0.f;
  const float w2R = (mrow < NHID) ? att_w2[mrow] : 0.f;
  __syncthreads();   // cwS/cbS visible to all waves

  // ---- staging: wave w stages ITS strip rows 16w..16w+15 (128 uint4).
  const uint4* gsrc = reinterpret_cast<const uint4*>(comH + (size_t)(b * NBAND) * 4096);
  uint4 pf[2];
  auto stage_issue = [&](int band) {
#pragma unroll
    for (int i = 0; i < 2; ++i) pf[i] = gsrc[band * 512 + w * 128 + i * 64 + lane];
  };
  auto stage_write = [&]() {
#pragma unroll
    for (int i = 0; i < 2; ++i) {
      const int idx = i * 64 + lane;          // within strip: 0..127
      const int row = 16 * w + (idx >> 3), slot = idx & 7;
      const int sb = (slot * 16) ^ ((row & 7) << 4);   // swizzled byte in row
      *reinterpret_cast<uint4*>(comS + row * 32 + sb / 4) = pf[i];
    }
  };

  auto a_frag = [&](int s) -> f16x8 {
    const int row = 16 * w + mrow;
    const int sb = (64 * s + 16 * g) ^ ((row & 7) << 4);
    return __builtin_bit_cast(f16x8, *reinterpret_cast<const uint4*>(comS + row * 32 + sb / 4));
  };

  _Float16* zSw = &zS[w][0];   // wave-private
  auto z_frag = [&](int s) -> f16x8 {
    // row = mrow, k = 32s+8g..+7; row byte stride 144 -> 16B-aligned
    return __builtin_bit_cast(f16x8,
        *reinterpret_cast<const uint4*>(zSw + mrow * ZSTR + 32 * s + 8 * g));
  };

  stage_issue(0);
  stage_write();

  f32x4 oacc[4];
#pragma unroll
  for (int n = 0; n < 4; ++n) oacc[n] = (f32x4){0.f, 0.f, 0.f, 0.f};
  float denom[4] = {0.f, 0.f, 0.f, 0.f};
  float mrun[4] = {-1e30f, -1e30f, -1e30f, -1e30f};

#pragma unroll 1
  for (int kb = 0; kb < NBAND; ++kb) {
    if (kb < NBAND - 1) stage_issue(kb + 1);   // T14: issue early

    // ---- MFMA z-GEMM: acc[n] = A(strip) x B[n], K=64 in 2 steps
    const f16x8 A0 = a_frag(0);
    const f16x8 A1 = a_frag(1);
    f32x4 acc[4];
#pragma unroll
    for (int n = 0; n < 4; ++n) {
      acc[n] = __builtin_amdgcn_mfma_f32_16x16x32_f16(A0, Bf[0][n], (f32x4){0.f, 0.f, 0.f, 0.f}, 0, 0, 0);
      acc[n] = __builtin_amdgcn_mfma_f32_16x16x32_f16(A1, Bf[1][n], acc[n], 0, 0, 0);
    }

    if (kb < NBAND - 1) stage_write();   // in-order DS: lands after A reads

    // ---- sigmoid in C-layout regs; write z to wave-private zS (f16)
    const float ck = cwS[kb], dk = cbS[kb];
#pragma unroll
    for (int n = 0; n < 4; ++n) {
      const float base = dk * rsumR[n] + lbR[n];
#pragma unroll
      for (int reg = 0; reg < 4; ++reg) {
        const float zv = 1.f / (1.f + __expf(-(ck * acc[n][reg] + base)));
        acc[n][reg] = zv;
        zSw[(4 * g + reg) * ZSTR + 16 * n + mrow] = (_Float16)zv;
      }
    }

    // ---- scorer via MFMA: p = z · w1^T (wave-local 16x16x64).
    // Same-wave DS in-order: z_frag reads see the writes above.
    float scr[4];
    {
      const f16x8 Z0 = z_frag(0);
      const f16x8 Z1 = z_frag(1);
      f32x4 pacc = __builtin_amdgcn_mfma_f32_16x16x32_f16(Z0, W1f[0], (f32x4){0.f, 0.f, 0.f, 0.f}, 0, 0, 0);
      pacc = __builtin_amdgcn_mfma_f32_16x16x32_f16(Z1, W1f[1], pacc, 0, 0, 0);
      // lane holds p[4g+reg][h=mrow]; tanh + w2 weight, sum over 16 h-lanes
#pragma unroll
      for (int reg = 0; reg < 4; ++reg) {
        const float ex = __expf(2.f * (pacc[reg] + b1R));
        float v = w2R * (1.f - 2.f / (ex + 1.f));
        v += __shfl_xor(v, 1, 64);
        v += __shfl_xor(v, 2, 64);
        v += __shfl_xor(v, 4, 64);
        v += __shfl_xor(v, 8, 64);
        scr[reg] = v;   // score[row 4g+reg], uniform within 16-lane group
      }
    }

    // ---- online softmax on C-layout accs (rows 4g+reg)
#pragma unroll
    for (int reg = 0; reg < 4; ++reg) {
      const float sc = scr[reg];
      const float nm = fmaxf(mrun[reg], sc);
      const float f = __expf(mrun[reg] - nm), e = __expf(sc - nm);
      denom[reg] = denom[reg] * f + e;
#pragma unroll
      for (int n = 0; n < 4; ++n)
        oacc[n][reg] = oacc[n][reg] * f + e * acc[n][reg];
      mrun[reg] = nm;
    }
  }

  // ---- store: r = 16w + 4g + reg, col = 16n + mrow
#pragma unroll
  for (int reg = 0; reg < 4; ++reg) {
    const int r = 16 * w + 4 * g + reg;
    if (r < NC) {
      const float inv = 1.f / denom[reg];
#pragma unroll
      for (int n = 0; n < 4; ++n) {
        const int col = 16 * n + mrow;
        if (col < NC) outp[(size_t)b * (NC * NC) + r * NC + col] = oacc[n][reg] * inv;
      }
    }
  }
}

// =====================================================================
// Kernel C: Chebyshev GCN + feature + 992->62 FC (unchanged).
// =====================================================================
__global__ __launch_bounds__(256) void k_cheb_fc(
    const float* __restrict__ de, const float* __restrict__ hidden,
    const float* __restrict__ essential, const float* __restrict__ gc_w,
    const float* __restrict__ gc_b, const float* __restrict__ fc_w,
    const float* __restrict__ fc_b, float* __restrict__ zmat) {
  const int b = blockIdx.x;
  __shared__ float hidS[NC * NC], essS[NC * NC];
  __shared__ float t0S[NC * NOUT], t1S[NC * NOUT];
  __shared__ float featS[NC * NOUT];
  __shared__ float deS[NC * NBAND];
  __shared__ float red2[256];
  const int tid = threadIdx.x;

  for (int t = tid; t < NC * NBAND; t += 256) deS[t] = de[b * NC * NBAND + t];
  for (int t = tid; t < NC * NC; t += 256) {
    hidS[t] = hidden[b * NC * NC + t];
    essS[t] = essential[b * NC * NC + t];
  }
  __syncthreads();
  for (int t = tid; t < NC * NOUT; t += 256) {
    const int i = t / NOUT, f = t % NOUT;
    float a0 = gc_b[f];
    float a1 = 0.f;
#pragma unroll
    for (int qq = 0; qq < NBAND; ++qq) {
      const float d = deS[i * NBAND + qq];
      a0 += d * gc_w[qq * NOUT + f];
      a1 += d * gc_w[(NBAND + qq) * NOUT + f];
    }
    t0S[t] = a0;
    t1S[t] = a1;
  }
  __syncthreads();
  for (int t = tid; t < NC * NOUT; t += 256) {
    const int i = t / NOUT, f = t % NOUT;
    float sh = 0.f, se = 0.f;
    for (int jj = 0; jj < NC; ++jj) {
      const float t1 = t1S[jj * NOUT + f];
      sh += hidS[i * NC + jj] * t1;
      se += essS[i * NC + jj] * t1;
    }
    const float gb1 = gc_b[NOUT + f];
    const float h = fmaxf(t0S[t] + sh + gb1, 0.f);
    const float e = fmaxf(t0S[t] + se + gb1, 0.f);
    featS[t] = 0.5f * (h + e);
  }
  __syncthreads();
  {
    const int n = tid >> 2, qq = tid & 3;
    float p = 0.f;
    if (n < NC) {
      const float* fw = fc_w + n * (NC * NOUT) + qq * 248;
      const float* fs = featS + qq * 248;
      for (int m = 0; m < 248; ++m) p += fs[m] * fw[m];
    }
    red2[tid] = p;
    __syncthreads();
    if (tid < NC) {
      const float z = red2[tid * 4] + red2[tid * 4 + 1] + red2[tid * 4 + 2] + red2[tid * 4 + 3] + fc_b[tid];
      zmat[b * NC + tid] = z;
    }
  }
}

// =====================================================================
// Kernel D1: batch-norm statistics (unchanged).
// =====================================================================
__global__ __launch_bounds__(256) void k_bnstats(
    const float* __restrict__ zmat, const float* __restrict__ bn_g,
    const float* __restrict__ bn_b, float* __restrict__ bnp) {
  const int n = blockIdx.x;
  __shared__ float rs[256], rq[256];
  const int tid = threadIdx.x;
  float s = 0.f, sq = 0.f;
  for (int r = tid; r < NB; r += 256) {
    const float v = zmat[r * NC + n];
    s += v;
    sq += v * v;
  }
  rs[tid] = s; rq[tid] = sq;
  __syncthreads();
  for (int st = 128; st > 0; st >>= 1) {
    if (tid < st) { rs[tid] += rs[tid + st]; rq[tid] += rq[tid + st]; }
    __syncthreads();
  }
  if (tid == 0) {
    const float mean = rs[0] * (1.f / NB);
    const float var = rq[0] * (1.f / NB) - mean * mean;
    const float sc = bn_g[n] * rsqrtf(var + 1e-5f);
    bnp[2 * n] = sc;
    bnp[2 * n + 1] = bn_b[n] - mean * sc;
  }
}

// =====================================================================
// Kernel D2: BN + sigmoid -> output1; 62->2 FC -> output (unchanged).
// =====================================================================
__global__ __launch_bounds__(64) void k_bn_out(
    const float* __restrict__ zmat, const float* __restrict__ bnp,
    const float* __restrict__ fc4_w, const float* __restrict__ fc4_b,
    float* __restrict__ out) {
  const int b = blockIdx.x;
  const int lane = threadIdx.x;
  float o1 = 0.f;
  if (lane < NC) {
    float z = zmat[b * NC + lane];
    z = z * bnp[2 * lane] + bnp[2 * lane + 1];
    o1 = 1.f / (1.f + __expf(-z));
    out[b * NC + lane] = o1;
  }
  float p0 = (lane < NC) ? o1 * fc4_w[lane] : 0.f;
  float p1 = (lane < NC) ? o1 * fc4_w[NC + lane] : 0.f;
#pragma unroll
  for (int off = 32; off > 0; off >>= 1) {
    p0 += __shfl_down(p0, off, 64);
    p1 += __shfl_down(p1, off, 64);
  }
  if (lane == 0) {
    out[NB * NC + b * 2 + 0] = p0 + fc4_b[0];
    out[NB * NC + b * 2 + 1] = p1 + fc4_b[1];
  }
}

extern "C" void kernel_launch(void* const* d_in, const int* in_sizes, int n_in,
                              void* d_out, int out_size, void* d_ws, size_t ws_size,
                              hipStream_t stream) {
  const float* de      = (const float*)d_in[0];
  const float* pcc     = (const float*)d_in[1];
  const float* Aadj    = (const float*)d_in[2];
  // d_in[3] conv_w, d_in[4] conv_b: dead (gate cancels in trace-normalized SPD)
  const float* hconv_w = (const float*)d_in[5];
  const float* hconv_b = (const float*)d_in[6];
  const float* hlin_w  = (const float*)d_in[7];
  const float* hlin_b  = (const float*)d_in[8];
  const float* econv_w = (const float*)d_in[9];
  const float* econv_b = (const float*)d_in[10];
  const float* elin_w  = (const float*)d_in[11];
  const float* elin_b  = (const float*)d_in[12];
  const float* att_w1  = (const float*)d_in[13];
  const float* att_b1  = (const float*)d_in[14];
  const float* att_w2  = (const float*)d_in[15];
  const float* gc_w    = (const float*)d_in[16];
  const float* gc_b    = (const float*)d_in[17];
  // d_in[18] wpar: wnorm = exp(w)/exp(w) = 1 exactly for 1-element wpar
  const float* fc_w    = (const float*)d_in[19];
  const float* fc_b    = (const float*)d_in[20];
  const float* bn_g    = (const float*)d_in[21];
  const float* bn_b    = (const float*)d_in[22];
  const float* fc4_w   = (const float*)d_in[23];
  const float* fc4_b   = (const float*)d_in[24];

  float* ws        = (float*)d_ws;
  _Float16* comH   = (_Float16*)ws;                      // 5120*4096 halves = 41.9 MB
  float* hidden    = ws + 10485760;                      //  3,936,256 floats
  float* essential = hidden + (size_t)NB * NC * NC;
  float* zmat      = essential + (size_t)NB * NC * NC;   //     63,488
  float* bnp       = zmat + (size_t)NB * NC;             //        128
  unsigned int* lwHg = (unsigned int*)(bnp + 128);       //      4,096 u32 (2 x 64 x 32)
  unsigned int* w1Hg = lwHg + 4096;                      //        512 u32 (16 x 32)
  float* rsumG     = (float*)(w1Hg + 512);               //        128
  // total ~74 MB of workspace

  k_spd<<<NB, 256, 0, stream>>>(pcc, Aadj, hlin_w, elin_w, att_w1,
                                comH, lwHg, w1Hg, rsumG);
  k_branch<<<NB * 2, 256, 0, stream>>>(comH, lwHg, w1Hg, rsumG,
      hconv_w, hconv_b, hlin_b,
      econv_w, econv_b, elin_b,
      att_b1, att_w2, hidden, essential);
  k_cheb_fc<<<NB, 256, 0, stream>>>(de, hidden, essential, gc_w, gc_b, fc_w, fc_b, zmat);
  k_bnstats<<<NC, 256, 0, stream>>>(zmat, bn_g, bn_b, bnp);
  k_bn_out<<<NB, 64, 0, stream>>>(zmat, bnp, fc4_w, fc4_b, (float*)d_out);
}

// Round 17
// 141.233 us; speedup vs baseline: 1.3188x; 1.0484x over previous
//
#include <hip/hip_runtime.h>
#include <math.h>

#define NB    1024
#define NC    62
#define NBAND 5
#define NOUT  16
#define NHID  10
#define ZSTR  72   // zS row stride in f16 (144B rows, 16B-aligned)
#define CLS   72   // pHcom row stride in f16 (144B rows, 16B-aligned; bank 4*row -> free 2-way)
#define CSLOT (64 * CLS)   // 4608 halves per band slot
#define XTW   34   // XcT row stride in u32

typedef __attribute__((ext_vector_type(4))) float f32x4;
typedef __attribute__((ext_vector_type(8))) _Float16 f16x8;
typedef __attribute__((ext_vector_type(2))) __fp16 fp16v2;   // cvt_pkrtz result type

__device__ __forceinline__ unsigned int pk2u(float x, float y) {
  const fp16v2 v = __builtin_amdgcn_cvt_pkrtz(x, y);
  return __builtin_bit_cast(unsigned int, v);
}

// =====================================================================
// Fused kernel: one block per b does SPD (all 5 bands) + both branches.
// SPD: pcc[b] read once dense -> relu -> pH[k][i][j] (stride 72). Per
// band: gather, center, scaled-pack XcT, MFMA SYRK (validated recipe);
// com[kb] OVERWRITES pH[kb]'s slot in LDS (slot fully consumed first).
// Branch: wave w's strip rows (16w..16w+15) are exactly the com rows
// wave w itself produced -> zero cross-wave deps, no barriers; z-GEMM
// and scorer both MFMA (validated recipes); weights loaded per block
// from f32 inputs (guarded float2 + pk2u). com never touches HBM.
// =====================================================================
__global__ __launch_bounds__(256, 2) void k_fused(
    const float* __restrict__ pcc, const float* __restrict__ Aadj,
    const float* __restrict__ hlin_w, const float* __restrict__ elin_w,
    const float* __restrict__ hconv_w, const float* __restrict__ hconv_b,
    const float* __restrict__ hlin_b,
    const float* __restrict__ econv_w, const float* __restrict__ econv_b,
    const float* __restrict__ elin_b,
    const float* __restrict__ att_w1, const float* __restrict__ att_b1,
    const float* __restrict__ att_w2,
    float* __restrict__ hiddenO, float* __restrict__ essentialO) {
  const int b = (blockIdx.x & 7) * 128 + (blockIdx.x >> 3);  // XCD swizzle
  __shared__ __align__(16) _Float16 pHcom[NBAND * CSLOT];    // 46,080 B
  __shared__ __align__(16) unsigned int XcT[64 * XTW];       //  8,704 B
  __shared__ __align__(16) _Float16 zS[4][16 * ZSTR];        //  9,216 B
  __shared__ float rsumL[2][64], lbL[2][64];
  __shared__ float cwL[2][8], cbL[2][8];
  __shared__ float red4a[4], red4b[4];

  const int tid = threadIdx.x;
  const int wave = tid >> 6, lane = tid & 63;
  const int p = tid >> 3, q8 = tid & 7, c0 = q8 * 8;
  const bool act = (p < 31);
  const int r0 = 2 * p, r1 = r0 + 1;
  const int mrow = lane & 15, g = lane >> 4;

  // ---- prologue params: rsum/lb (coop), cw/cb
  if (tid < 128) {
    const int pbr = tid >> 6, col = tid & 63;
    const float* lwsrc = pbr ? elin_w : hlin_w;
    float s = 0.f;
    if (col < NC) {
      const float* rowp = lwsrc + col * NC;
#pragma unroll
      for (int e = 0; e < 31; ++e) {
        const float2 v = *reinterpret_cast<const float2*>(rowp + 2 * e);
        s += v.x + v.y;
      }
    }
    rsumL[pbr][col] = s;
    lbL[pbr][col] = (col < NC) ? (pbr ? elin_b : hlin_b)[col] : 0.f;
  }
  if (tid < NBAND) {
    cwL[0][tid] = hconv_w[tid]; cbL[0][tid] = hconv_b[tid];
    cwL[1][tid] = econv_w[tid]; cbL[1][tid] = econv_b[tid];
  }

  float ld0[8], ld1[8];   // pcc band centered values
  float lA0[8], lA1[8];   // Aadj band prefetch / centered values

  auto center = [&](float (&a0)[8], float (&a1)[8], float* red) -> void {
    float s0 = 0.f, s1 = 0.f;
#pragma unroll
    for (int u = 0; u < 8; ++u) { s0 += a0[u]; s1 += a1[u]; }
    s0 += __shfl_xor(s0, 1, 64); s0 += __shfl_xor(s0, 2, 64); s0 += __shfl_xor(s0, 4, 64);
    s1 += __shfl_xor(s1, 1, 64); s1 += __shfl_xor(s1, 2, 64); s1 += __shfl_xor(s1, 4, 64);
    const float m0 = s0 * (1.f / NC), m1 = s1 * (1.f / NC);
    float sq = 0.f;
#pragma unroll
    for (int u = 0; u < 8; ++u) {
      const bool in = act && (c0 + u < NC);
      const float cv0 = in ? (a0[u] - m0) : 0.f;
      const float cv1 = in ? (a1[u] - m1) : 0.f;
      a0[u] = cv0;
      a1[u] = cv1;
      sq += cv0 * cv0 + cv1 * cv1;
    }
#pragma unroll
    for (int off = 1; off < 64; off <<= 1) sq += __shfl_xor(sq, off, 64);
    if (lane == 0) red[wave] = sq;
  };

  auto xct_write = [&](const float (&a0)[8], const float (&a1)[8], float sc) -> void {
#pragma unroll
    for (int u = 0; u < 8; ++u)
      XcT[(c0 + u) * XTW + p] = pk2u(sc * a0[u], sc * a1[u]);
  };

  auto fragread = [&](int row, int s) -> f16x8 {
    const unsigned int* pp = &XcT[row * XTW + 16 * s + 4 * g];
    const uint2 a = *reinterpret_cast<const uint2*>(pp);
    const uint2 b2 = *reinterpret_cast<const uint2*>(pp + 2);
    const uint4 v = make_uint4(a.x, a.y, b2.x, b2.y);
    return __builtin_bit_cast(f16x8, v);
  };

  // ---- Phase A: dense pcc[b] read, relu, scatter ALL elements to pH
  {
    const float4* src = reinterpret_cast<const float4*>(pcc + (size_t)b * (NC * NC * NBAND));
#pragma unroll
    for (int it = 0; it < 19; ++it) {
      const int fidx = tid + it * 256;
      if (fidx < 4805) {                       // 19220 floats / 4 exactly
        const float4 v = src[fidx];
        const int g0 = 4 * fidx;
        int i = g0 / 310;
        int rem = g0 - i * 310;
        int j = rem / 5;
        int k = rem - j * 5;
        const float vals[4] = {v.x, v.y, v.z, v.w};
#pragma unroll
        for (int e = 0; e < 4; ++e) {
          pHcom[k * CSLOT + i * CLS + j] = (_Float16)fmaxf(vals[e], 0.f);
          if (++k == 5) { k = 0; if (++j == NC) { j = 0; ++i; } }
        }
      }
    }
  }
  __syncthreads();   // pH + params ready

  // ==================== SPD band loop ====================
#pragma unroll 1
  for (int kb = 0; kb < NBAND; ++kb) {
    const int bk = b * NBAND + kb;

    // issue Aadj band kb loads (coalesced float2; land by src1 phase)
#pragma unroll
    for (int u = 0; u < 8; ++u) { lA0[u] = 0.f; lA1[u] = 0.f; }
    if (act) {
      const float* a0p = Aadj + ((size_t)bk * NC + r0) * NC + c0;
      const float* a1p = Aadj + ((size_t)bk * NC + r1) * NC + c0;
#pragma unroll
      for (int e = 0; e < 4; ++e) {
        const int c = c0 + 2 * e;
        if (c + 1 < NC) {
          const float2 v0 = *reinterpret_cast<const float2*>(a0p + 2 * e);
          const float2 v1 = *reinterpret_cast<const float2*>(a1p + 2 * e);
          lA0[2 * e] = v0.x; lA0[2 * e + 1] = v0.y;
          lA1[2 * e] = v1.x; lA1[2 * e + 1] = v1.y;
        } else if (c < NC) {
          lA0[2 * e] = a0p[2 * e];
          lA1[2 * e] = a1p[2 * e];
        }
      }
    }

    // gather pH band kb rows (relu already applied)
#pragma unroll
    for (int u = 0; u < 8; ++u) { ld0[u] = 0.f; ld1[u] = 0.f; }
    if (act) {
      const _Float16* ph = pHcom + kb * CSLOT;
#pragma unroll
      for (int u = 0; u < 8; ++u) {
        const int c = c0 + u;
        if (c < NC) {
          ld0[u] = (float)ph[r0 * CLS + c];
          ld1[u] = (float)ph[r1 * CLS + c];
        }
      }
    }
    center(ld0, ld1, red4a);
    __syncthreads();   // (1) red4a ready; prev band's MFMA XcT reads done

    const float tra0 = red4a[0] + red4a[1] + red4a[2] + red4a[3];
    xct_write(ld0, ld1, sqrtf(0.5f / tra0));
    __syncthreads();   // (2) XcT(src0) ready

    f32x4 acc[4];
#pragma unroll
    for (int n = 0; n < 4; ++n) acc[n] = (f32x4){0.f, 0.f, 0.f, 0.f};
    {
      const f16x8 A0 = fragread(16 * wave + mrow, 0);
      const f16x8 A1 = fragread(16 * wave + mrow, 1);
#pragma unroll
      for (int n = 0; n < 4; ++n) {
        const f16x8 B0 = fragread(16 * n + mrow, 0);
        const f16x8 B1 = fragread(16 * n + mrow, 1);
        acc[n] = __builtin_amdgcn_mfma_f32_16x16x32_f16(A0, B0, acc[n], 0, 0, 0);
        acc[n] = __builtin_amdgcn_mfma_f32_16x16x32_f16(A1, B1, acc[n], 0, 0, 0);
      }
    }

    // src1 = Aadj band: relu + center (VALU overlaps MFMA)
#pragma unroll
    for (int u = 0; u < 8; ++u) { lA0[u] = fmaxf(lA0[u], 0.f); lA1[u] = fmaxf(lA1[u], 0.f); }
    center(lA0, lA1, red4b);
    __syncthreads();   // (3) red4b ready; MFMA src0 XcT reads done

    const float tra1 = red4b[0] + red4b[1] + red4b[2] + red4b[3];
    xct_write(lA0, lA1, sqrtf(0.5f / tra1));
    __syncthreads();   // (4) XcT(src1) ready

    {
      const f16x8 A0 = fragread(16 * wave + mrow, 0);
      const f16x8 A1 = fragread(16 * wave + mrow, 1);
#pragma unroll
      for (int n = 0; n < 4; ++n) {
        const f16x8 B0 = fragread(16 * n + mrow, 0);
        const f16x8 B1 = fragread(16 * n + mrow, 1);
        acc[n] = __builtin_amdgcn_mfma_f32_16x16x32_f16(A0, B0, acc[n], 0, 0, 0);
        acc[n] = __builtin_amdgcn_mfma_f32_16x16x32_f16(A1, B1, acc[n], 0, 0, 0);
      }
    }

    // epilogue: diag + f16 store INTO pH[kb]'s slot (fully consumed above).
    // r = 16*wave+4g+reg (own-wave rows), col = 16n+mrow.
    {
      _Float16* comL = pHcom + kb * CSLOT;
#pragma unroll
      for (int reg = 0; reg < 4; ++reg) {
        const int r = 16 * wave + 4 * g + reg;
#pragma unroll
        for (int n = 0; n < 4; ++n) {
          float v = acc[n][reg];
          if (n == wave && mrow == 4 * g + reg) v += 1e-5f;   // diagonal
          comL[r * CLS + 16 * n + mrow] = (_Float16)v;
        }
      }
    }
  }
  // no barrier needed: branch phase only reads wave-own com rows + params

  // ==================== branch phase (both br) ====================
  // W1f (scorer B-frags, h=mrow<10 else zero) + b1/w2 once
  f16x8 W1f[2];
#pragma unroll
  for (int s = 0; s < 2; ++s) {
    unsigned int pk[4] = {0u, 0u, 0u, 0u};
    if (mrow < NHID) {
#pragma unroll
      for (int e = 0; e < 4; ++e) {
        const int c = 32 * s + 8 * g + 2 * e;
        if (c + 1 < NC) {
          const float2 v = *reinterpret_cast<const float2*>(att_w1 + mrow * NC + c);
          pk[e] = pk2u(v.x, v.y);
        }
      }
    }
    W1f[s] = __builtin_bit_cast(f16x8, make_uint4(pk[0], pk[1], pk[2], pk[3]));
  }
  const float b1R = (mrow < NHID) ? att_b1[mrow] : 0.f;
  const float w2R = (mrow < NHID) ? att_w2[mrow] : 0.f;

  _Float16* zSw = &zS[wave][0];
  auto z_frag = [&](int s) -> f16x8 {
    return __builtin_bit_cast(f16x8,
        *reinterpret_cast<const uint4*>(zSw + mrow * ZSTR + 32 * s + 8 * g));
  };
  auto a_frag = [&](int kb, int s) -> f16x8 {
    return __builtin_bit_cast(f16x8,
        *reinterpret_cast<const uint4*>(pHcom + kb * CSLOT + (16 * wave + mrow) * CLS + 32 * s + 8 * g));
  };

#pragma unroll 1
  for (int br = 0; br < 2; ++br) {
    const float* __restrict__ lwsrc = br ? elin_w : hlin_w;
    float* __restrict__ outp = br ? essentialO : hiddenO;

    // Bf: lw rows (cols of z) as f16 frags; col = 16n+mrow, k = 32s+8g..+7
    f16x8 Bf[2][4];
    float rsumR[4], lbR[4];
#pragma unroll
    for (int n = 0; n < 4; ++n) {
      const int col = 16 * n + mrow;
      rsumR[n] = rsumL[br][col];
      lbR[n] = lbL[br][col];
#pragma unroll
      for (int s = 0; s < 2; ++s) {
        unsigned int pk[4] = {0u, 0u, 0u, 0u};
        if (col < NC) {
#pragma unroll
          for (int e = 0; e < 4; ++e) {
            const int c = 32 * s + 8 * g + 2 * e;
            if (c + 1 < NC) {
              const float2 v = *reinterpret_cast<const float2*>(lwsrc + col * NC + c);
              pk[e] = pk2u(v.x, v.y);
            }
          }
        }
        Bf[s][n] = __builtin_bit_cast(f16x8, make_uint4(pk[0], pk[1], pk[2], pk[3]));
      }
    }

    f32x4 oacc[4];
#pragma unroll
    for (int n = 0; n < 4; ++n) oacc[n] = (f32x4){0.f, 0.f, 0.f, 0.f};
    float denom[4] = {0.f, 0.f, 0.f, 0.f};
    float mrun[4] = {-1e30f, -1e30f, -1e30f, -1e30f};

#pragma unroll 1
    for (int kb = 0; kb < NBAND; ++kb) {
      // ---- MFMA z-GEMM: acc[n] = com(strip) x lw[n], K=64 in 2 steps
      const f16x8 A0 = a_frag(kb, 0);
      const f16x8 A1 = a_frag(kb, 1);
      f32x4 acc[4];
#pragma unroll
      for (int n = 0; n < 4; ++n) {
        acc[n] = __builtin_amdgcn_mfma_f32_16x16x32_f16(A0, Bf[0][n], (f32x4){0.f, 0.f, 0.f, 0.f}, 0, 0, 0);
        acc[n] = __builtin_amdgcn_mfma_f32_16x16x32_f16(A1, Bf[1][n], acc[n], 0, 0, 0);
      }

      // ---- sigmoid in C-layout regs; write z to wave-private zS (f16)
      const float ck = cwL[br][kb], dk = cbL[br][kb];
#pragma unroll
      for (int n = 0; n < 4; ++n) {
        const float base = dk * rsumR[n] + lbR[n];
#pragma unroll
        for (int reg = 0; reg < 4; ++reg) {
          const float zv = 1.f / (1.f + __expf(-(ck * acc[n][reg] + base)));
          acc[n][reg] = zv;
          zSw[(4 * g + reg) * ZSTR + 16 * n + mrow] = (_Float16)zv;
        }
      }

      // ---- scorer via MFMA (same-wave DS in-order)
      float scr[4];
      {
        const f16x8 Z0 = z_frag(0);
        const f16x8 Z1 = z_frag(1);
        f32x4 pacc = __builtin_amdgcn_mfma_f32_16x16x32_f16(Z0, W1f[0], (f32x4){0.f, 0.f, 0.f, 0.f}, 0, 0, 0);
        pacc = __builtin_amdgcn_mfma_f32_16x16x32_f16(Z1, W1f[1], pacc, 0, 0, 0);
#pragma unroll
        for (int reg = 0; reg < 4; ++reg) {
          const float ex = __expf(2.f * (pacc[reg] + b1R));
          float v = w2R * (1.f - 2.f / (ex + 1.f));
          v += __shfl_xor(v, 1, 64);
          v += __shfl_xor(v, 2, 64);
          v += __shfl_xor(v, 4, 64);
          v += __shfl_xor(v, 8, 64);
          scr[reg] = v;   // score[row 4g+reg]
        }
      }

      // ---- online softmax on C-layout accs
#pragma unroll
      for (int reg = 0; reg < 4; ++reg) {
        const float sc = scr[reg];
        const float nm = fmaxf(mrun[reg], sc);
        const float f = __expf(mrun[reg] - nm), e = __expf(sc - nm);
        denom[reg] = denom[reg] * f + e;
#pragma unroll
        for (int n = 0; n < 4; ++n)
          oacc[n][reg] = oacc[n][reg] * f + e * acc[n][reg];
        mrun[reg] = nm;
      }
    }

    // ---- store: r = 16*wave + 4g + reg, col = 16n + mrow
#pragma unroll
    for (int reg = 0; reg < 4; ++reg) {
      const int r = 16 * wave + 4 * g + reg;
      if (r < NC) {
        const float inv = 1.f / denom[reg];
#pragma unroll
        for (int n = 0; n < 4; ++n) {
          const int col = 16 * n + mrow;
          if (col < NC) outp[(size_t)b * (NC * NC) + r * NC + col] = oacc[n][reg] * inv;
        }
      }
    }
  }
}

// =====================================================================
// Kernel C: Chebyshev GCN + feature + 992->62 FC (unchanged).
// =====================================================================
__global__ __launch_bounds__(256) void k_cheb_fc(
    const float* __restrict__ de, const float* __restrict__ hidden,
    const float* __restrict__ essential, const float* __restrict__ gc_w,
    const float* __restrict__ gc_b, const float* __restrict__ fc_w,
    const float* __restrict__ fc_b, float* __restrict__ zmat) {
  const int b = blockIdx.x;
  __shared__ float hidS[NC * NC], essS[NC * NC];
  __shared__ float t0S[NC * NOUT], t1S[NC * NOUT];
  __shared__ float featS[NC * NOUT];
  __shared__ float deS[NC * NBAND];
  __shared__ float red2[256];
  const int tid = threadIdx.x;

  for (int t = tid; t < NC * NBAND; t += 256) deS[t] = de[b * NC * NBAND + t];
  for (int t = tid; t < NC * NC; t += 256) {
    hidS[t] = hidden[b * NC * NC + t];
    essS[t] = essential[b * NC * NC + t];
  }
  __syncthreads();
  for (int t = tid; t < NC * NOUT; t += 256) {
    const int i = t / NOUT, f = t % NOUT;
    float a0 = gc_b[f];
    float a1 = 0.f;
#pragma unroll
    for (int qq = 0; qq < NBAND; ++qq) {
      const float d = deS[i * NBAND + qq];
      a0 += d * gc_w[qq * NOUT + f];
      a1 += d * gc_w[(NBAND + qq) * NOUT + f];
    }
    t0S[t] = a0;
    t1S[t] = a1;
  }
  __syncthreads();
  for (int t = tid; t < NC * NOUT; t += 256) {
    const int i = t / NOUT, f = t % NOUT;
    float sh = 0.f, se = 0.f;
    for (int jj = 0; jj < NC; ++jj) {
      const float t1 = t1S[jj * NOUT + f];
      sh += hidS[i * NC + jj] * t1;
      se += essS[i * NC + jj] * t1;
    }
    const float gb1 = gc_b[NOUT + f];
    const float h = fmaxf(t0S[t] + sh + gb1, 0.f);
    const float e = fmaxf(t0S[t] + se + gb1, 0.f);
    featS[t] = 0.5f * (h + e);
  }
  __syncthreads();
  {
    const int n = tid >> 2, qq = tid & 3;
    float p = 0.f;
    if (n < NC) {
      const float* fw = fc_w + n * (NC * NOUT) + qq * 248;
      const float* fs = featS + qq * 248;
      for (int m = 0; m < 248; ++m) p += fs[m] * fw[m];
    }
    red2[tid] = p;
    __syncthreads();
    if (tid < NC) {
      const float z = red2[tid * 4] + red2[tid * 4 + 1] + red2[tid * 4 + 2] + red2[tid * 4 + 3] + fc_b[tid];
      zmat[b * NC + tid] = z;
    }
  }
}

// =====================================================================
// Kernel D1: batch-norm statistics (unchanged).
// =====================================================================
__global__ __launch_bounds__(256) void k_bnstats(
    const float* __restrict__ zmat, const float* __restrict__ bn_g,
    const float* __restrict__ bn_b, float* __restrict__ bnp) {
  const int n = blockIdx.x;
  __shared__ float rs[256], rq[256];
  const int tid = threadIdx.x;
  float s = 0.f, sq = 0.f;
  for (int r = tid; r < NB; r += 256) {
    const float v = zmat[r * NC + n];
    s += v;
    sq += v * v;
  }
  rs[tid] = s; rq[tid] = sq;
  __syncthreads();
  for (int st = 128; st > 0; st >>= 1) {
    if (tid < st) { rs[tid] += rs[tid + st]; rq[tid] += rq[tid + st]; }
    __syncthreads();
  }
  if (tid == 0) {
    const float mean = rs[0] * (1.f / NB);
    const float var = rq[0] * (1.f / NB) - mean * mean;
    const float sc = bn_g[n] * rsqrtf(var + 1e-5f);
    bnp[2 * n] = sc;
    bnp[2 * n + 1] = bn_b[n] - mean * sc;
  }
}

// =====================================================================
// Kernel D2: BN + sigmoid -> output1; 62->2 FC -> output (unchanged).
// =====================================================================
__global__ __launch_bounds__(64) void k_bn_out(
    const float* __restrict__ zmat, const float* __restrict__ bnp,
    const float* __restrict__ fc4_w, const float* __restrict__ fc4_b,
    float* __restrict__ out) {
  const int b = blockIdx.x;
  const int lane = threadIdx.x;
  float o1 = 0.f;
  if (lane < NC) {
    float z = zmat[b * NC + lane];
    z = z * bnp[2 * lane] + bnp[2 * lane + 1];
    o1 = 1.f / (1.f + __expf(-z));
    out[b * NC + lane] = o1;
  }
  float p0 = (lane < NC) ? o1 * fc4_w[lane] : 0.f;
  float p1 = (lane < NC) ? o1 * fc4_w[NC + lane] : 0.f;
#pragma unroll
  for (int off = 32; off > 0; off >>= 1) {
    p0 += __shfl_down(p0, off, 64);
    p1 += __shfl_down(p1, off, 64);
  }
  if (lane == 0) {
    out[NB * NC + b * 2 + 0] = p0 + fc4_b[0];
    out[NB * NC + b * 2 + 1] = p1 + fc4_b[1];
  }
}

extern "C" void kernel_launch(void* const* d_in, const int* in_sizes, int n_in,
                              void* d_out, int out_size, void* d_ws, size_t ws_size,
                              hipStream_t stream) {
  const float* de      = (const float*)d_in[0];
  const float* pcc     = (const float*)d_in[1];
  const float* Aadj    = (const float*)d_in[2];
  // d_in[3] conv_w, d_in[4] conv_b: dead (gate cancels in trace-normalized SPD)
  const float* hconv_w = (const float*)d_in[5];
  const float* hconv_b = (const float*)d_in[6];
  const float* hlin_w  = (const float*)d_in[7];
  const float* hlin_b  = (const float*)d_in[8];
  const float* econv_w = (const float*)d_in[9];
  const float* econv_b = (const float*)d_in[10];
  const float* elin_w  = (const float*)d_in[11];
  const float* elin_b  = (const float*)d_in[12];
  const float* att_w1  = (const float*)d_in[13];
  const float* att_b1  = (const float*)d_in[14];
  const float* att_w2  = (const float*)d_in[15];
  const float* gc_w    = (const float*)d_in[16];
  const float* gc_b    = (const float*)d_in[17];
  // d_in[18] wpar: wnorm = exp(w)/exp(w) = 1 exactly for 1-element wpar
  const float* fc_w    = (const float*)d_in[19];
  const float* fc_b    = (const float*)d_in[20];
  const float* bn_g    = (const float*)d_in[21];
  const float* bn_b    = (const float*)d_in[22];
  const float* fc4_w   = (const float*)d_in[23];
  const float* fc4_b   = (const float*)d_in[24];

  float* ws        = (float*)d_ws;
  float* hidden    = ws;                                 // 3,936,256 floats
  float* essential = hidden + (size_t)NB * NC * NC;      // 3,936,256
  float* zmat      = essential + (size_t)NB * NC * NC;   //    63,488
  float* bnp       = zmat + (size_t)NB * NC;             //       128
  // total ~32 MB of workspace (comH eliminated — com lives in LDS)

  k_fused<<<NB, 256, 0, stream>>>(pcc, Aadj, hlin_w, elin_w,
      hconv_w, hconv_b, hlin_b,
      econv_w, econv_b, elin_b,
      att_w1, att_b1, att_w2, hidden, essential);
  k_cheb_fc<<<NB, 256, 0, stream>>>(de, hidden, essential, gc_w, gc_b, fc_w, fc_b, zmat);
  k_bnstats<<<NC, 256, 0, stream>>>(zmat, bn_g, bn_b, bnp);
  k_bn_out<<<NB, 64, 0, stream>>>(zmat, bnp, fc4_w, fc4_b, (float*)d_out);
}

// Round 18
// 116.568 us; speedup vs baseline: 1.5978x; 1.2116x over previous
//
#include <hip/hip_runtime.h>
#include <math.h>

#define NB    1024
#define NC    62
#define NBAND 5
#define NOUT  16
#define NHID  10
#define ZSTR  72   // zS row stride in f16 (144B rows, 16B-aligned)
#define CLS   72   // pHcom row stride in f16
#define CSLOT (64 * CLS)   // 4608 halves per band slot
#define XTW   34   // XcT row stride in u32

typedef __attribute__((ext_vector_type(4))) float f32x4;
typedef __attribute__((ext_vector_type(8))) _Float16 f16x8;
typedef __attribute__((ext_vector_type(2))) __fp16 fp16v2;   // cvt_pkrtz result type

__device__ __forceinline__ unsigned int pk2u(float x, float y) {
  const fp16v2 v = __builtin_amdgcn_cvt_pkrtz(x, y);
  return __builtin_bit_cast(unsigned int, v);
}

// =====================================================================
// Fully fused kernel: one block per b does SPD (5 bands) + both
// branches + Chebyshev GCN + feature + 992->62 FC -> zmat[b].
// hidden/essential NEVER touch HBM: each wave's final adjacency strip
// goes (f16) into its zS strip buffer and feeds one more MFMA
// (adj @ t1, t1T frags per-lane from de/gc_w1, j>=62 zeroed).
// XcT is aliased as featS/red2 after SPD (barrier-protected).
// =====================================================================
__global__ __launch_bounds__(256, 2) void k_fused(
    const float* __restrict__ pcc, const float* __restrict__ Aadj,
    const float* __restrict__ hlin_w, const float* __restrict__ elin_w,
    const float* __restrict__ hconv_w, const float* __restrict__ hconv_b,
    const float* __restrict__ hlin_b,
    const float* __restrict__ econv_w, const float* __restrict__ econv_b,
    const float* __restrict__ elin_b,
    const float* __restrict__ att_w1, const float* __restrict__ att_b1,
    const float* __restrict__ att_w2,
    const float* __restrict__ de, const float* __restrict__ gc_w,
    const float* __restrict__ gc_b, const float* __restrict__ fc_w,
    const float* __restrict__ fc_b, float* __restrict__ zmat) {
  const int b = (blockIdx.x & 7) * 128 + (blockIdx.x >> 3);  // XCD swizzle
  __shared__ __align__(16) _Float16 pHcom[NBAND * CSLOT];    // 46,080 B
  __shared__ __align__(16) unsigned int XcT[64 * XTW];       //  8,704 B (aliased later)
  __shared__ __align__(16) _Float16 zS[4][16 * ZSTR];        //  9,216 B
  __shared__ float deS[NC * NBAND + 2];                      //  1,248 B
  __shared__ float rsumL[2][64], lbL[2][64];
  __shared__ float cwL[2][8], cbL[2][8];
  __shared__ float red4a[4], red4b[4];

  const int tid = threadIdx.x;
  const int wave = tid >> 6, lane = tid & 63;
  const int p = tid >> 3, q8 = tid & 7, c0 = q8 * 8;
  const bool act = (p < 31);
  const int r0 = 2 * p, r1 = r0 + 1;
  const int mrow = lane & 15, g = lane >> 4;

  // ---- prologue params: rsum/lb (coop), cw/cb, de
  if (tid < 128) {
    const int pbr = tid >> 6, col = tid & 63;
    const float* lwsrc = pbr ? elin_w : hlin_w;
    float s = 0.f;
    if (col < NC) {
      const float* rowp = lwsrc + col * NC;
#pragma unroll
      for (int e = 0; e < 31; ++e) {
        const float2 v = *reinterpret_cast<const float2*>(rowp + 2 * e);
        s += v.x + v.y;
      }
    }
    rsumL[pbr][col] = s;
    lbL[pbr][col] = (col < NC) ? (pbr ? elin_b : hlin_b)[col] : 0.f;
  }
  if (tid < NBAND) {
    cwL[0][tid] = hconv_w[tid]; cbL[0][tid] = hconv_b[tid];
    cwL[1][tid] = econv_w[tid]; cbL[1][tid] = econv_b[tid];
  }
  for (int t = tid; t < NC * NBAND; t += 256) deS[t] = de[(size_t)b * (NC * NBAND) + t];

  float ld0[8], ld1[8];   // pcc band centered values
  float lA0[8], lA1[8];   // Aadj band prefetch / centered values

  auto center = [&](float (&a0)[8], float (&a1)[8], float* red) -> void {
    float s0 = 0.f, s1 = 0.f;
#pragma unroll
    for (int u = 0; u < 8; ++u) { s0 += a0[u]; s1 += a1[u]; }
    s0 += __shfl_xor(s0, 1, 64); s0 += __shfl_xor(s0, 2, 64); s0 += __shfl_xor(s0, 4, 64);
    s1 += __shfl_xor(s1, 1, 64); s1 += __shfl_xor(s1, 2, 64); s1 += __shfl_xor(s1, 4, 64);
    const float m0 = s0 * (1.f / NC), m1 = s1 * (1.f / NC);
    float sq = 0.f;
#pragma unroll
    for (int u = 0; u < 8; ++u) {
      const bool in = act && (c0 + u < NC);
      const float cv0 = in ? (a0[u] - m0) : 0.f;
      const float cv1 = in ? (a1[u] - m1) : 0.f;
      a0[u] = cv0;
      a1[u] = cv1;
      sq += cv0 * cv0 + cv1 * cv1;
    }
#pragma unroll
    for (int off = 1; off < 64; off <<= 1) sq += __shfl_xor(sq, off, 64);
    if (lane == 0) red[wave] = sq;
  };

  auto xct_write = [&](const float (&a0)[8], const float (&a1)[8], float sc) -> void {
#pragma unroll
    for (int u = 0; u < 8; ++u)
      XcT[(c0 + u) * XTW + p] = pk2u(sc * a0[u], sc * a1[u]);
  };

  auto fragread = [&](int row, int s) -> f16x8 {
    const unsigned int* pp = &XcT[row * XTW + 16 * s + 4 * g];
    const uint2 a = *reinterpret_cast<const uint2*>(pp);
    const uint2 b2 = *reinterpret_cast<const uint2*>(pp + 2);
    const uint4 v = make_uint4(a.x, a.y, b2.x, b2.y);
    return __builtin_bit_cast(f16x8, v);
  };

  // ---- Phase A: dense pcc[b] read, relu, scatter ALL elements to pH
  {
    const float4* src = reinterpret_cast<const float4*>(pcc + (size_t)b * (NC * NC * NBAND));
#pragma unroll
    for (int it = 0; it < 19; ++it) {
      const int fidx = tid + it * 256;
      if (fidx < 4805) {                       // 19220 floats / 4 exactly
        const float4 v = src[fidx];
        const int g0 = 4 * fidx;
        int i = g0 / 310;
        int rem = g0 - i * 310;
        int j = rem / 5;
        int k = rem - j * 5;
        const float vals[4] = {v.x, v.y, v.z, v.w};
#pragma unroll
        for (int e = 0; e < 4; ++e) {
          pHcom[k * CSLOT + i * CLS + j] = (_Float16)fmaxf(vals[e], 0.f);
          if (++k == 5) { k = 0; if (++j == NC) { j = 0; ++i; } }
        }
      }
    }
  }
  __syncthreads();   // pH + params + deS ready

  // ==================== SPD band loop ====================
#pragma unroll 1
  for (int kb = 0; kb < NBAND; ++kb) {
    const int bk = b * NBAND + kb;

    // issue Aadj band kb loads (coalesced float2; land by src1 phase)
#pragma unroll
    for (int u = 0; u < 8; ++u) { lA0[u] = 0.f; lA1[u] = 0.f; }
    if (act) {
      const float* a0p = Aadj + ((size_t)bk * NC + r0) * NC + c0;
      const float* a1p = Aadj + ((size_t)bk * NC + r1) * NC + c0;
#pragma unroll
      for (int e = 0; e < 4; ++e) {
        const int c = c0 + 2 * e;
        if (c + 1 < NC) {
          const float2 v0 = *reinterpret_cast<const float2*>(a0p + 2 * e);
          const float2 v1 = *reinterpret_cast<const float2*>(a1p + 2 * e);
          lA0[2 * e] = v0.x; lA0[2 * e + 1] = v0.y;
          lA1[2 * e] = v1.x; lA1[2 * e + 1] = v1.y;
        } else if (c < NC) {
          lA0[2 * e] = a0p[2 * e];
          lA1[2 * e] = a1p[2 * e];
        }
      }
    }

    // gather pH band kb rows (relu already applied)
#pragma unroll
    for (int u = 0; u < 8; ++u) { ld0[u] = 0.f; ld1[u] = 0.f; }
    if (act) {
      const _Float16* ph = pHcom + kb * CSLOT;
#pragma unroll
      for (int u = 0; u < 8; ++u) {
        const int c = c0 + u;
        if (c < NC) {
          ld0[u] = (float)ph[r0 * CLS + c];
          ld1[u] = (float)ph[r1 * CLS + c];
        }
      }
    }
    center(ld0, ld1, red4a);
    __syncthreads();   // (1) red4a ready; prev band's MFMA XcT reads done

    const float tra0 = red4a[0] + red4a[1] + red4a[2] + red4a[3];
    xct_write(ld0, ld1, sqrtf(0.5f / tra0));
    __syncthreads();   // (2) XcT(src0) ready

    f32x4 acc[4];
#pragma unroll
    for (int n = 0; n < 4; ++n) acc[n] = (f32x4){0.f, 0.f, 0.f, 0.f};
    {
      const f16x8 A0 = fragread(16 * wave + mrow, 0);
      const f16x8 A1 = fragread(16 * wave + mrow, 1);
#pragma unroll
      for (int n = 0; n < 4; ++n) {
        const f16x8 B0 = fragread(16 * n + mrow, 0);
        const f16x8 B1 = fragread(16 * n + mrow, 1);
        acc[n] = __builtin_amdgcn_mfma_f32_16x16x32_f16(A0, B0, acc[n], 0, 0, 0);
        acc[n] = __builtin_amdgcn_mfma_f32_16x16x32_f16(A1, B1, acc[n], 0, 0, 0);
      }
    }

    // src1 = Aadj band: relu + center (VALU overlaps MFMA)
#pragma unroll
    for (int u = 0; u < 8; ++u) { lA0[u] = fmaxf(lA0[u], 0.f); lA1[u] = fmaxf(lA1[u], 0.f); }
    center(lA0, lA1, red4b);
    __syncthreads();   // (3) red4b ready; MFMA src0 XcT reads done

    const float tra1 = red4b[0] + red4b[1] + red4b[2] + red4b[3];
    xct_write(lA0, lA1, sqrtf(0.5f / tra1));
    __syncthreads();   // (4) XcT(src1) ready

    {
      const f16x8 A0 = fragread(16 * wave + mrow, 0);
      const f16x8 A1 = fragread(16 * wave + mrow, 1);
#pragma unroll
      for (int n = 0; n < 4; ++n) {
        const f16x8 B0 = fragread(16 * n + mrow, 0);
        const f16x8 B1 = fragread(16 * n + mrow, 1);
        acc[n] = __builtin_amdgcn_mfma_f32_16x16x32_f16(A0, B0, acc[n], 0, 0, 0);
        acc[n] = __builtin_amdgcn_mfma_f32_16x16x32_f16(A1, B1, acc[n], 0, 0, 0);
      }
    }

    // epilogue: diag + f16 store INTO pH[kb]'s slot (fully consumed above).
    {
      _Float16* comL = pHcom + kb * CSLOT;
#pragma unroll
      for (int reg = 0; reg < 4; ++reg) {
        const int r = 16 * wave + 4 * g + reg;
#pragma unroll
        for (int n = 0; n < 4; ++n) {
          float v = acc[n][reg];
          if (n == wave && mrow == 4 * g + reg) v += 1e-5f;   // diagonal
          comL[r * CLS + 16 * n + mrow] = (_Float16)v;
        }
      }
    }
  }
  // no barrier: branch phase reads wave-own com rows + prologue params only

  // ==================== branch + cheb phase ====================
  // scorer W1f (h=mrow<10 else zero) + b1/w2
  f16x8 W1f[2];
#pragma unroll
  for (int s = 0; s < 2; ++s) {
    unsigned int pk[4] = {0u, 0u, 0u, 0u};
    if (mrow < NHID) {
#pragma unroll
      for (int e = 0; e < 4; ++e) {
        const int c = 32 * s + 8 * g + 2 * e;
        if (c + 1 < NC) {
          const float2 v = *reinterpret_cast<const float2*>(att_w1 + mrow * NC + c);
          pk[e] = pk2u(v.x, v.y);
        }
      }
    }
    W1f[s] = __builtin_bit_cast(f16x8, make_uint4(pk[0], pk[1], pk[2], pk[3]));
  }
  const float b1R = (mrow < NHID) ? att_b1[mrow] : 0.f;
  const float w2R = (mrow < NHID) ? att_w2[mrow] : 0.f;

  // cheb per-lane operands: T1f (B-frags of t1T[f=mrow][j], j>=62 zeroed),
  // t0R (rows 16w+4g+reg, col mrow), gb1R2
  f16x8 T1f[2];
  float t0R[4], gb1R2;
  {
    float gw1c[5], gw0c[5];
#pragma unroll
    for (int q = 0; q < 5; ++q) {
      gw0c[q] = gc_w[q * NOUT + mrow];
      gw1c[q] = gc_w[(NBAND + q) * NOUT + mrow];
    }
    const float gb0 = gc_b[mrow];
    gb1R2 = gc_b[NOUT + mrow];
#pragma unroll
    for (int s = 0; s < 2; ++s) {
      unsigned int pk[4];
#pragma unroll
      for (int e2 = 0; e2 < 4; ++e2) {
        const int j0 = 32 * s + 8 * g + 2 * e2, j1 = j0 + 1;
        float a = 0.f, bb = 0.f;
        if (j0 < NC) {
#pragma unroll
          for (int q = 0; q < 5; ++q) a += deS[j0 * 5 + q] * gw1c[q];
        }
        if (j1 < NC) {
#pragma unroll
          for (int q = 0; q < 5; ++q) bb += deS[j1 * 5 + q] * gw1c[q];
        }
        pk[e2] = pk2u(a, bb);
      }
      T1f[s] = __builtin_bit_cast(f16x8, make_uint4(pk[0], pk[1], pk[2], pk[3]));
    }
#pragma unroll
    for (int reg = 0; reg < 4; ++reg) {
      const int r = 16 * wave + 4 * g + reg;
      float t = 0.f;
      if (r < NC) {
        t = gb0;
#pragma unroll
        for (int q = 0; q < 5; ++q) t += deS[r * 5 + q] * gw0c[q];
      }
      t0R[reg] = t;
    }
  }

  _Float16* zSw = &zS[wave][0];
  auto z_frag = [&](int s) -> f16x8 {
    return __builtin_bit_cast(f16x8,
        *reinterpret_cast<const uint4*>(zSw + mrow * ZSTR + 32 * s + 8 * g));
  };
  auto a_frag = [&](int kb, int s) -> f16x8 {
    return __builtin_bit_cast(f16x8,
        *reinterpret_cast<const uint4*>(pHcom + kb * CSLOT + (16 * wave + mrow) * CLS + 32 * s + 8 * g));
  };

  float facc[4] = {0.f, 0.f, 0.f, 0.f};   // feature accumulator (C-layout)

#pragma unroll 1
  for (int br = 0; br < 2; ++br) {
    const float* __restrict__ lwsrc = br ? elin_w : hlin_w;

    // Bf: lw rows as f16 frags; col = 16n+mrow, k = 32s+8g..+7
    f16x8 Bf[2][4];
    float rsumR[4], lbR[4];
#pragma unroll
    for (int n = 0; n < 4; ++n) {
      const int col = 16 * n + mrow;
      rsumR[n] = rsumL[br][col];
      lbR[n] = lbL[br][col];
#pragma unroll
      for (int s = 0; s < 2; ++s) {
        unsigned int pk[4] = {0u, 0u, 0u, 0u};
        if (col < NC) {
#pragma unroll
          for (int e = 0; e < 4; ++e) {
            const int c = 32 * s + 8 * g + 2 * e;
            if (c + 1 < NC) {
              const float2 v = *reinterpret_cast<const float2*>(lwsrc + col * NC + c);
              pk[e] = pk2u(v.x, v.y);
            }
          }
        }
        Bf[s][n] = __builtin_bit_cast(f16x8, make_uint4(pk[0], pk[1], pk[2], pk[3]));
      }
    }

    f32x4 oacc[4];
#pragma unroll
    for (int n = 0; n < 4; ++n) oacc[n] = (f32x4){0.f, 0.f, 0.f, 0.f};
    float denom[4] = {0.f, 0.f, 0.f, 0.f};
    float mrun[4] = {-1e30f, -1e30f, -1e30f, -1e30f};

#pragma unroll 1
    for (int kb = 0; kb < NBAND; ++kb) {
      // ---- MFMA z-GEMM: acc[n] = com(strip) x lw[n], K=64 in 2 steps
      const f16x8 A0 = a_frag(kb, 0);
      const f16x8 A1 = a_frag(kb, 1);
      f32x4 acc[4];
#pragma unroll
      for (int n = 0; n < 4; ++n) {
        acc[n] = __builtin_amdgcn_mfma_f32_16x16x32_f16(A0, Bf[0][n], (f32x4){0.f, 0.f, 0.f, 0.f}, 0, 0, 0);
        acc[n] = __builtin_amdgcn_mfma_f32_16x16x32_f16(A1, Bf[1][n], acc[n], 0, 0, 0);
      }

      // ---- sigmoid in C-layout regs; write z to wave-private zS (f16)
      const float ck = cwL[br][kb], dk = cbL[br][kb];
#pragma unroll
      for (int n = 0; n < 4; ++n) {
        const float base = dk * rsumR[n] + lbR[n];
#pragma unroll
        for (int reg = 0; reg < 4; ++reg) {
          const float zv = 1.f / (1.f + __expf(-(ck * acc[n][reg] + base)));
          acc[n][reg] = zv;
          zSw[(4 * g + reg) * ZSTR + 16 * n + mrow] = (_Float16)zv;
        }
      }

      // ---- scorer via MFMA (same-wave DS in-order)
      float scr[4];
      {
        const f16x8 Z0 = z_frag(0);
        const f16x8 Z1 = z_frag(1);
        f32x4 pacc = __builtin_amdgcn_mfma_f32_16x16x32_f16(Z0, W1f[0], (f32x4){0.f, 0.f, 0.f, 0.f}, 0, 0, 0);
        pacc = __builtin_amdgcn_mfma_f32_16x16x32_f16(Z1, W1f[1], pacc, 0, 0, 0);
#pragma unroll
        for (int reg = 0; reg < 4; ++reg) {
          const float ex = __expf(2.f * (pacc[reg] + b1R));
          float v = w2R * (1.f - 2.f / (ex + 1.f));
          v += __shfl_xor(v, 1, 64);
          v += __shfl_xor(v, 2, 64);
          v += __shfl_xor(v, 4, 64);
          v += __shfl_xor(v, 8, 64);
          scr[reg] = v;   // score[row 4g+reg]
        }
      }

      // ---- online softmax on C-layout accs
#pragma unroll
      for (int reg = 0; reg < 4; ++reg) {
        const float sc = scr[reg];
        const float nm = fmaxf(mrun[reg], sc);
        const float f = __expf(mrun[reg] - nm), e = __expf(sc - nm);
        denom[reg] = denom[reg] * f + e;
#pragma unroll
        for (int n = 0; n < 4; ++n)
          oacc[n][reg] = oacc[n][reg] * f + e * acc[n][reg];
        mrun[reg] = nm;
      }
    }

    // ---- adjacency strip (f16) into zSw (z dead; same-wave in-order)
#pragma unroll
    for (int reg = 0; reg < 4; ++reg) {
      const float inv = 1.f / denom[reg];
#pragma unroll
      for (int n = 0; n < 4; ++n)
        zSw[(4 * g + reg) * ZSTR + 16 * n + mrow] = (_Float16)(oacc[n][reg] * inv);
    }

    // ---- cheb MFMA: ch = adj_strip @ t1 (pad cols j>=62 have t1=0)
    {
      const f16x8 H0 = z_frag(0);
      const f16x8 H1 = z_frag(1);
      f32x4 ch = __builtin_amdgcn_mfma_f32_16x16x32_f16(H0, T1f[0], (f32x4){0.f, 0.f, 0.f, 0.f}, 0, 0, 0);
      ch = __builtin_amdgcn_mfma_f32_16x16x32_f16(H1, T1f[1], ch, 0, 0, 0);
#pragma unroll
      for (int reg = 0; reg < 4; ++reg)
        facc[reg] += 0.5f * fmaxf(t0R[reg] + ch[reg] + gb1R2, 0.f);
    }
  }

  // ==================== feature -> FC -> zmat ====================
  __syncthreads();   // all waves done with XcT (SPD) before aliasing
  float* featS = reinterpret_cast<float*>(XcT);          // 64*16 floats
  float* red2  = reinterpret_cast<float*>(XcT) + 1024;   // 256 floats
#pragma unroll
  for (int reg = 0; reg < 4; ++reg) {
    const int r = 16 * wave + 4 * g + reg;   // rows 62,63 written, never read
    featS[r * NOUT + mrow] = facc[reg];
  }
  __syncthreads();
  {
    const int n = tid >> 2, qq = tid & 3;
    float ps = 0.f;
    if (n < NC) {
      const float* fw = fc_w + n * (NC * NOUT) + qq * 248;
      const float* fs = featS + qq * 248;
      for (int m = 0; m < 248; ++m) ps += fs[m] * fw[m];
    }
    red2[tid] = ps;
    __syncthreads();
    if (tid < NC) {
      zmat[(size_t)b * NC + tid] =
          red2[tid * 4] + red2[tid * 4 + 1] + red2[tid * 4 + 2] + red2[tid * 4 + 3] + fc_b[tid];
    }
  }
}

// =====================================================================
// Kernel D1: batch-norm statistics (unchanged).
// =====================================================================
__global__ __launch_bounds__(256) void k_bnstats(
    const float* __restrict__ zmat, const float* __restrict__ bn_g,
    const float* __restrict__ bn_b, float* __restrict__ bnp) {
  const int n = blockIdx.x;
  __shared__ float rs[256], rq[256];
  const int tid = threadIdx.x;
  float s = 0.f, sq = 0.f;
  for (int r = tid; r < NB; r += 256) {
    const float v = zmat[r * NC + n];
    s += v;
    sq += v * v;
  }
  rs[tid] = s; rq[tid] = sq;
  __syncthreads();
  for (int st = 128; st > 0; st >>= 1) {
    if (tid < st) { rs[tid] += rs[tid + st]; rq[tid] += rq[tid + st]; }
    __syncthreads();
  }
  if (tid == 0) {
    const float mean = rs[0] * (1.f / NB);
    const float var = rq[0] * (1.f / NB) - mean * mean;
    const float sc = bn_g[n] * rsqrtf(var + 1e-5f);
    bnp[2 * n] = sc;
    bnp[2 * n + 1] = bn_b[n] - mean * sc;
  }
}

// =====================================================================
// Kernel D2: BN + sigmoid -> output1; 62->2 FC -> output (unchanged).
// =====================================================================
__global__ __launch_bounds__(64) void k_bn_out(
    const float* __restrict__ zmat, const float* __restrict__ bnp,
    const float* __restrict__ fc4_w, const float* __restrict__ fc4_b,
    float* __restrict__ out) {
  const int b = blockIdx.x;
  const int lane = threadIdx.x;
  float o1 = 0.f;
  if (lane < NC) {
    float z = zmat[b * NC + lane];
    z = z * bnp[2 * lane] + bnp[2 * lane + 1];
    o1 = 1.f / (1.f + __expf(-z));
    out[b * NC + lane] = o1;
  }
  float p0 = (lane < NC) ? o1 * fc4_w[lane] : 0.f;
  float p1 = (lane < NC) ? o1 * fc4_w[NC + lane] : 0.f;
#pragma unroll
  for (int off = 32; off > 0; off >>= 1) {
    p0 += __shfl_down(p0, off, 64);
    p1 += __shfl_down(p1, off, 64);
  }
  if (lane == 0) {
    out[NB * NC + b * 2 + 0] = p0 + fc4_b[0];
    out[NB * NC + b * 2 + 1] = p1 + fc4_b[1];
  }
}

extern "C" void kernel_launch(void* const* d_in, const int* in_sizes, int n_in,
                              void* d_out, int out_size, void* d_ws, size_t ws_size,
                              hipStream_t stream) {
  const float* de      = (const float*)d_in[0];
  const float* pcc     = (const float*)d_in[1];
  const float* Aadj    = (const float*)d_in[2];
  // d_in[3] conv_w, d_in[4] conv_b: dead (gate cancels in trace-normalized SPD)
  const float* hconv_w = (const float*)d_in[5];
  const float* hconv_b = (const float*)d_in[6];
  const float* hlin_w  = (const float*)d_in[7];
  const float* hlin_b  = (const float*)d_in[8];
  const float* econv_w = (const float*)d_in[9];
  const float* econv_b = (const float*)d_in[10];
  const float* elin_w  = (const float*)d_in[11];
  const float* elin_b  = (const float*)d_in[12];
  const float* att_w1  = (const float*)d_in[13];
  const float* att_b1  = (const float*)d_in[14];
  const float* att_w2  = (const float*)d_in[15];
  const float* gc_w    = (const float*)d_in[16];
  const float* gc_b    = (const float*)d_in[17];
  // d_in[18] wpar: wnorm = exp(w)/exp(w) = 1 exactly for 1-element wpar
  const float* fc_w    = (const float*)d_in[19];
  const float* fc_b    = (const float*)d_in[20];
  const float* bn_g    = (const float*)d_in[21];
  const float* bn_b    = (const float*)d_in[22];
  const float* fc4_w   = (const float*)d_in[23];
  const float* fc4_b   = (const float*)d_in[24];

  float* ws   = (float*)d_ws;
  float* zmat = ws;                        // 63,488 floats
  float* bnp  = zmat + (size_t)NB * NC;    // 128
  // total ~0.25 MB of workspace (hidden/essential/com all live in LDS)

  k_fused<<<NB, 256, 0, stream>>>(pcc, Aadj, hlin_w, elin_w,
      hconv_w, hconv_b, hlin_b,
      econv_w, econv_b, elin_b,
      att_w1, att_b1, att_w2,
      de, gc_w, gc_b, fc_w, fc_b, zmat);
  k_bnstats<<<NC, 256, 0, stream>>>(zmat, bn_g, bn_b, bnp);
  k_bn_out<<<NB, 64, 0, stream>>>(zmat, bnp, fc4_w, fc4_b, (float*)d_out);
}

// Round 19
// 110.211 us; speedup vs baseline: 1.6900x; 1.0577x over previous
//
#include <hip/hip_runtime.h>
#include <math.h>

#define NB    1024
#define NC    62
#define NBAND 5
#define NOUT  16
#define NHID  10
#define ZSTR  72   // zS row stride in f16 (144B rows, 16B-aligned)
#define CLS   72   // pHcom row stride in f16
#define CSLOT (64 * CLS)   // 4608 halves per band slot
#define XTW   34   // XcT row stride in u32

typedef __attribute__((ext_vector_type(4))) float f32x4;
typedef __attribute__((ext_vector_type(8))) _Float16 f16x8;
typedef __attribute__((ext_vector_type(2))) __fp16 fp16v2;   // cvt_pkrtz result type

__device__ __forceinline__ unsigned int pk2u(float x, float y) {
  const fp16v2 v = __builtin_amdgcn_cvt_pkrtz(x, y);
  return __builtin_bit_cast(unsigned int, v);
}

// =====================================================================
// k_init (1 block): pre-pack lwHg row-major f16 [br][o][c], w1Hg
// (16 rows, h>=10 zero), rsumG — so k_fused loads 10 uint4/thread
// instead of ~260 guarded gathers. (Round-15/16 validated code.)
// =====================================================================
__global__ __launch_bounds__(256) void k_init(
    const float* __restrict__ hlin_w, const float* __restrict__ elin_w,
    const float* __restrict__ att_w1,
    unsigned int* __restrict__ lwHg, unsigned int* __restrict__ w1Hg,
    float* __restrict__ rsumG) {
  const int tid = threadIdx.x;
  for (int t = tid; t < 2 * 64 * 32; t += 256) {
    const int brx = t >> 11, rem = t & 2047, o = rem >> 5, cp = rem & 31;
    const float* lwsrc = brx ? elin_w : hlin_w;
    float lo = 0.f, hi = 0.f;
    if (o < NC) {
      const int c = 2 * cp;
      if (c < NC)     lo = lwsrc[o * NC + c];
      if (c + 1 < NC) hi = lwsrc[o * NC + c + 1];
    }
    lwHg[t] = pk2u(lo, hi);
  }
  for (int t = tid; t < 16 * 32; t += 256) {
    const int h = t >> 5, op = t & 31;
    float lo = 0.f, hi = 0.f;
    if (h < NHID) {
      if (2 * op < NC)     lo = att_w1[h * NC + 2 * op];
      if (2 * op + 1 < NC) hi = att_w1[h * NC + 2 * op + 1];
    }
    w1Hg[t] = pk2u(lo, hi);
  }
  if (tid < 128) {
    const int pbr = tid >> 6, col = tid & 63;
    const float* lwsrc = pbr ? elin_w : hlin_w;
    float s = 0.f;
    if (col < NC)
      for (int c = 0; c < NC; ++c) s += lwsrc[col * NC + c];
    rsumG[pbr * 64 + col] = s;
  }
}

// =====================================================================
// Fully fused kernel (v2): SPD (5 bands) + both branches + Chebyshev +
// feature + FC -> zmat[b], one block per b. Changes vs round 18:
//  - XcT DOUBLE buffer + post-MFMA trace scaling -> 2 barriers/band
//  - Bf/W1f/rsum from pre-packed globals (10 uint4/thread)
//  - FC reads fc_w as coalesced float4 interleave
// =====================================================================
__global__ __launch_bounds__(256, 2) void k_fused(
    const float* __restrict__ pcc, const float* __restrict__ Aadj,
    const unsigned int* __restrict__ lwHg, const unsigned int* __restrict__ w1Hg,
    const float* __restrict__ rsumG,
    const float* __restrict__ hconv_w, const float* __restrict__ hconv_b,
    const float* __restrict__ hlin_b,
    const float* __restrict__ econv_w, const float* __restrict__ econv_b,
    const float* __restrict__ elin_b,
    const float* __restrict__ att_b1, const float* __restrict__ att_w2,
    const float* __restrict__ de, const float* __restrict__ gc_w,
    const float* __restrict__ gc_b, const float* __restrict__ fc_w,
    const float* __restrict__ fc_b, float* __restrict__ zmat) {
  const int b = (blockIdx.x & 7) * 128 + (blockIdx.x >> 3);  // XCD swizzle
  __shared__ __align__(16) _Float16 pHcom[NBAND * CSLOT];    // 46,080 B
  __shared__ __align__(16) unsigned int XcT[2][64 * XTW];    // 17,408 B (aliased later)
  __shared__ __align__(16) _Float16 zS[4][16 * ZSTR];        //  9,216 B
  __shared__ float deS[NC * NBAND + 2];                      //  1,248 B
  __shared__ float cwL[2][8], cbL[2][8];
  __shared__ float red4a[4], red4b[4];

  const int tid = threadIdx.x;
  const int wave = tid >> 6, lane = tid & 63;
  const int p = tid >> 3, q8 = tid & 7, c0 = q8 * 8;
  const bool act = (p < 31);
  const int r0 = 2 * p, r1 = r0 + 1;
  const int mrow = lane & 15, g = lane >> 4;

  if (tid < NBAND) {
    cwL[0][tid] = hconv_w[tid]; cbL[0][tid] = hconv_b[tid];
    cwL[1][tid] = econv_w[tid]; cbL[1][tid] = econv_b[tid];
  }
  for (int t = tid; t < NC * NBAND; t += 256) deS[t] = de[(size_t)b * (NC * NBAND) + t];

  float ld0[8], ld1[8];   // pcc band centered values
  float lA0[8], lA1[8];   // Aadj band prefetch / centered values

  auto center = [&](float (&a0)[8], float (&a1)[8], float* red) -> void {
    float s0 = 0.f, s1 = 0.f;
#pragma unroll
    for (int u = 0; u < 8; ++u) { s0 += a0[u]; s1 += a1[u]; }
    s0 += __shfl_xor(s0, 1, 64); s0 += __shfl_xor(s0, 2, 64); s0 += __shfl_xor(s0, 4, 64);
    s1 += __shfl_xor(s1, 1, 64); s1 += __shfl_xor(s1, 2, 64); s1 += __shfl_xor(s1, 4, 64);
    const float m0 = s0 * (1.f / NC), m1 = s1 * (1.f / NC);
    float sq = 0.f;
#pragma unroll
    for (int u = 0; u < 8; ++u) {
      const bool in = act && (c0 + u < NC);
      const float cv0 = in ? (a0[u] - m0) : 0.f;
      const float cv1 = in ? (a1[u] - m1) : 0.f;
      a0[u] = cv0;
      a1[u] = cv1;
      sq += cv0 * cv0 + cv1 * cv1;
    }
#pragma unroll
    for (int off = 1; off < 64; off <<= 1) sq += __shfl_xor(sq, off, 64);
    if (lane == 0) red[wave] = sq;
  };

  auto xct_write = [&](unsigned int* X, const float (&a0)[8], const float (&a1)[8]) -> void {
#pragma unroll
    for (int u = 0; u < 8; ++u)
      X[(c0 + u) * XTW + p] = pk2u(a0[u], a1[u]);   // UNSCALED (scale post-MFMA)
  };

  auto fragread = [&](const unsigned int* X, int row, int s) -> f16x8 {
    const unsigned int* pp = &X[row * XTW + 16 * s + 4 * g];
    const uint2 a = *reinterpret_cast<const uint2*>(pp);
    const uint2 b2 = *reinterpret_cast<const uint2*>(pp + 2);
    const uint4 v = make_uint4(a.x, a.y, b2.x, b2.y);
    return __builtin_bit_cast(f16x8, v);
  };

  auto syrk = [&](const unsigned int* X, f32x4 (&acc)[4]) -> void {
    const f16x8 A0 = fragread(X, 16 * wave + mrow, 0);
    const f16x8 A1 = fragread(X, 16 * wave + mrow, 1);
#pragma unroll
    for (int n = 0; n < 4; ++n) {
      const f16x8 B0 = fragread(X, 16 * n + mrow, 0);
      const f16x8 B1 = fragread(X, 16 * n + mrow, 1);
      acc[n] = __builtin_amdgcn_mfma_f32_16x16x32_f16(A0, B0, acc[n], 0, 0, 0);
      acc[n] = __builtin_amdgcn_mfma_f32_16x16x32_f16(A1, B1, acc[n], 0, 0, 0);
    }
  };

  // ---- Phase A: dense pcc[b] read, relu, scatter ALL elements to pH
  {
    const float4* src = reinterpret_cast<const float4*>(pcc + (size_t)b * (NC * NC * NBAND));
#pragma unroll
    for (int it = 0; it < 19; ++it) {
      const int fidx = tid + it * 256;
      if (fidx < 4805) {                       // 19220 floats / 4 exactly
        const float4 v = src[fidx];
        const int g0 = 4 * fidx;
        int i = g0 / 310;
        int rem = g0 - i * 310;
        int j = rem / 5;
        int k = rem - j * 5;
        const float vals[4] = {v.x, v.y, v.z, v.w};
#pragma unroll
        for (int e = 0; e < 4; ++e) {
          pHcom[k * CSLOT + i * CLS + j] = (_Float16)fmaxf(vals[e], 0.f);
          if (++k == 5) { k = 0; if (++j == NC) { j = 0; ++i; } }
        }
      }
    }
  }
  __syncthreads();   // pH + params + deS ready

  // ==================== SPD band loop (2 barriers/band) ====================
#pragma unroll 1
  for (int kb = 0; kb < NBAND; ++kb) {
    const int bk = b * NBAND + kb;

    // issue Aadj band kb loads (coalesced float2; land by src1 phase)
#pragma unroll
    for (int u = 0; u < 8; ++u) { lA0[u] = 0.f; lA1[u] = 0.f; }
    if (act) {
      const float* a0p = Aadj + ((size_t)bk * NC + r0) * NC + c0;
      const float* a1p = Aadj + ((size_t)bk * NC + r1) * NC + c0;
#pragma unroll
      for (int e = 0; e < 4; ++e) {
        const int c = c0 + 2 * e;
        if (c + 1 < NC) {
          const float2 v0 = *reinterpret_cast<const float2*>(a0p + 2 * e);
          const float2 v1 = *reinterpret_cast<const float2*>(a1p + 2 * e);
          lA0[2 * e] = v0.x; lA0[2 * e + 1] = v0.y;
          lA1[2 * e] = v1.x; lA1[2 * e + 1] = v1.y;
        } else if (c < NC) {
          lA0[2 * e] = a0p[2 * e];
          lA1[2 * e] = a1p[2 * e];
        }
      }
    }

    // gather pH band kb rows (relu already applied), center, pack buf0
#pragma unroll
    for (int u = 0; u < 8; ++u) { ld0[u] = 0.f; ld1[u] = 0.f; }
    if (act) {
      const _Float16* ph = pHcom + kb * CSLOT;
#pragma unroll
      for (int u = 0; u < 8; ++u) {
        const int c = c0 + u;
        if (c < NC) {
          ld0[u] = (float)ph[r0 * CLS + c];
          ld1[u] = (float)ph[r1 * CLS + c];
        }
      }
    }
    center(ld0, ld1, red4a);
    xct_write(XcT[0], ld0, ld1);
    __syncthreads();   // (A) XcT0 + red4a ready; prev-band XcT1 reads done

    const float tra0 = red4a[0] + red4a[1] + red4a[2] + red4a[3];
    f32x4 acc0[4];
#pragma unroll
    for (int n = 0; n < 4; ++n) acc0[n] = (f32x4){0.f, 0.f, 0.f, 0.f};
    syrk(XcT[0], acc0);

    // src1 = Aadj band: relu + center + pack buf1 (VALU overlaps MFMA)
#pragma unroll
    for (int u = 0; u < 8; ++u) { lA0[u] = fmaxf(lA0[u], 0.f); lA1[u] = fmaxf(lA1[u], 0.f); }
    center(lA0, lA1, red4b);
    xct_write(XcT[1], lA0, lA1);
    __syncthreads();   // (B) XcT1 + red4b ready; XcT0 reads done

    const float tra1 = red4b[0] + red4b[1] + red4b[2] + red4b[3];
    f32x4 acc1[4];
#pragma unroll
    for (int n = 0; n < 4; ++n) acc1[n] = (f32x4){0.f, 0.f, 0.f, 0.f};
    syrk(XcT[1], acc1);

    // epilogue: post-scale + diag + f16 store INTO pH[kb]'s slot
    {
      const float s0 = 0.5f / tra0, s1 = 0.5f / tra1;
      _Float16* comL = pHcom + kb * CSLOT;
#pragma unroll
      for (int reg = 0; reg < 4; ++reg) {
        const int r = 16 * wave + 4 * g + reg;
#pragma unroll
        for (int n = 0; n < 4; ++n) {
          float v = acc0[n][reg] * s0 + acc1[n][reg] * s1;
          if (n == wave && mrow == 4 * g + reg) v += 1e-5f;   // diagonal
          comL[r * CLS + 16 * n + mrow] = (_Float16)v;
        }
      }
    }
  }
  // no barrier: branch phase reads wave-own com rows + prologue params only

  // ==================== branch + cheb phase ====================
  f16x8 W1f[2];
#pragma unroll
  for (int s = 0; s < 2; ++s) {
    const uint4 v = *reinterpret_cast<const uint4*>(w1Hg + mrow * 32 + s * 16 + g * 4);
    W1f[s] = __builtin_bit_cast(f16x8, v);
  }
  const float b1R = (mrow < NHID) ? att_b1[mrow] : 0.f;
  const float w2R = (mrow < NHID) ? att_w2[mrow] : 0.f;

  // cheb per-lane operands
  f16x8 T1f[2];
  float t0R[4], gb1R2;
  {
    float gw1c[5], gw0c[5];
#pragma unroll
    for (int q = 0; q < 5; ++q) {
      gw0c[q] = gc_w[q * NOUT + mrow];
      gw1c[q] = gc_w[(NBAND + q) * NOUT + mrow];
    }
    const float gb0 = gc_b[mrow];
    gb1R2 = gc_b[NOUT + mrow];
#pragma unroll
    for (int s = 0; s < 2; ++s) {
      unsigned int pk[4];
#pragma unroll
      for (int e2 = 0; e2 < 4; ++e2) {
        const int j0 = 32 * s + 8 * g + 2 * e2, j1 = j0 + 1;
        float a = 0.f, bb = 0.f;
        if (j0 < NC) {
#pragma unroll
          for (int q = 0; q < 5; ++q) a += deS[j0 * 5 + q] * gw1c[q];
        }
        if (j1 < NC) {
#pragma unroll
          for (int q = 0; q < 5; ++q) bb += deS[j1 * 5 + q] * gw1c[q];
        }
        pk[e2] = pk2u(a, bb);
      }
      T1f[s] = __builtin_bit_cast(f16x8, make_uint4(pk[0], pk[1], pk[2], pk[3]));
    }
#pragma unroll
    for (int reg = 0; reg < 4; ++reg) {
      const int r = 16 * wave + 4 * g + reg;
      float t = 0.f;
      if (r < NC) {
        t = gb0;
#pragma unroll
        for (int q = 0; q < 5; ++q) t += deS[r * 5 + q] * gw0c[q];
      }
      t0R[reg] = t;
    }
  }

  _Float16* zSw = &zS[wave][0];
  auto z_frag = [&](int s) -> f16x8 {
    return __builtin_bit_cast(f16x8,
        *reinterpret_cast<const uint4*>(zSw + mrow * ZSTR + 32 * s + 8 * g));
  };
  auto a_frag = [&](int kb, int s) -> f16x8 {
    return __builtin_bit_cast(f16x8,
        *reinterpret_cast<const uint4*>(pHcom + kb * CSLOT + (16 * wave + mrow) * CLS + 32 * s + 8 * g));
  };

  float facc[4] = {0.f, 0.f, 0.f, 0.f};   // feature accumulator (C-layout)

#pragma unroll 1
  for (int br = 0; br < 2; ++br) {
    const float* __restrict__ lb = br ? elin_b : hlin_b;

    // Bf from pre-packed lwHg (validated recipe); rsum/lb per-lane
    f16x8 Bf[2][4];
    float rsumR[4], lbR[4];
#pragma unroll
    for (int n = 0; n < 4; ++n) {
      const int col = 16 * n + mrow;
      rsumR[n] = rsumG[br * 64 + col];
      lbR[n] = (col < NC) ? lb[col] : 0.f;
#pragma unroll
      for (int s = 0; s < 2; ++s) {
        const uint4 v = *reinterpret_cast<const uint4*>(lwHg + br * 2048 + col * 32 + s * 16 + g * 4);
        Bf[s][n] = __builtin_bit_cast(f16x8, v);
      }
    }

    f32x4 oacc[4];
#pragma unroll
    for (int n = 0; n < 4; ++n) oacc[n] = (f32x4){0.f, 0.f, 0.f, 0.f};
    float denom[4] = {0.f, 0.f, 0.f, 0.f};
    float mrun[4] = {-1e30f, -1e30f, -1e30f, -1e30f};

#pragma unroll 1
    for (int kb = 0; kb < NBAND; ++kb) {
      // ---- MFMA z-GEMM: acc[n] = com(strip) x lw[n], K=64 in 2 steps
      const f16x8 A0 = a_frag(kb, 0);
      const f16x8 A1 = a_frag(kb, 1);
      f32x4 acc[4];
#pragma unroll
      for (int n = 0; n < 4; ++n) {
        acc[n] = __builtin_amdgcn_mfma_f32_16x16x32_f16(A0, Bf[0][n], (f32x4){0.f, 0.f, 0.f, 0.f}, 0, 0, 0);
        acc[n] = __builtin_amdgcn_mfma_f32_16x16x32_f16(A1, Bf[1][n], acc[n], 0, 0, 0);
      }

      // ---- sigmoid in C-layout regs; write z to wave-private zS (f16)
      const float ck = cwL[br][kb], dk = cbL[br][kb];
#pragma unroll
      for (int n = 0; n < 4; ++n) {
        const float base = dk * rsumR[n] + lbR[n];
#pragma unroll
        for (int reg = 0; reg < 4; ++reg) {
          const float zv = 1.f / (1.f + __expf(-(ck * acc[n][reg] + base)));
          acc[n][reg] = zv;
          zSw[(4 * g + reg) * ZSTR + 16 * n + mrow] = (_Float16)zv;
        }
      }

      // ---- scorer via MFMA (same-wave DS in-order)
      float scr[4];
      {
        const f16x8 Z0 = z_frag(0);
        const f16x8 Z1 = z_frag(1);
        f32x4 pacc = __builtin_amdgcn_mfma_f32_16x16x32_f16(Z0, W1f[0], (f32x4){0.f, 0.f, 0.f, 0.f}, 0, 0, 0);
        pacc = __builtin_amdgcn_mfma_f32_16x16x32_f16(Z1, W1f[1], pacc, 0, 0, 0);
#pragma unroll
        for (int reg = 0; reg < 4; ++reg) {
          const float ex = __expf(2.f * (pacc[reg] + b1R));
          float v = w2R * (1.f - 2.f / (ex + 1.f));
          v += __shfl_xor(v, 1, 64);
          v += __shfl_xor(v, 2, 64);
          v += __shfl_xor(v, 4, 64);
          v += __shfl_xor(v, 8, 64);
          scr[reg] = v;   // score[row 4g+reg]
        }
      }

      // ---- online softmax on C-layout accs
#pragma unroll
      for (int reg = 0; reg < 4; ++reg) {
        const float sc = scr[reg];
        const float nm = fmaxf(mrun[reg], sc);
        const float f = __expf(mrun[reg] - nm), e = __expf(sc - nm);
        denom[reg] = denom[reg] * f + e;
#pragma unroll
        for (int n = 0; n < 4; ++n)
          oacc[n][reg] = oacc[n][reg] * f + e * acc[n][reg];
        mrun[reg] = nm;
      }
    }

    // ---- adjacency strip (f16) into zSw (z dead; same-wave in-order)
#pragma unroll
    for (int reg = 0; reg < 4; ++reg) {
      const float inv = 1.f / denom[reg];
#pragma unroll
      for (int n = 0; n < 4; ++n)
        zSw[(4 * g + reg) * ZSTR + 16 * n + mrow] = (_Float16)(oacc[n][reg] * inv);
    }

    // ---- cheb MFMA: ch = adj_strip @ t1 (pad cols j>=62 have t1=0)
    {
      const f16x8 H0 = z_frag(0);
      const f16x8 H1 = z_frag(1);
      f32x4 ch = __builtin_amdgcn_mfma_f32_16x16x32_f16(H0, T1f[0], (f32x4){0.f, 0.f, 0.f, 0.f}, 0, 0, 0);
      ch = __builtin_amdgcn_mfma_f32_16x16x32_f16(H1, T1f[1], ch, 0, 0, 0);
#pragma unroll
      for (int reg = 0; reg < 4; ++reg)
        facc[reg] += 0.5f * fmaxf(t0R[reg] + ch[reg] + gb1R2, 0.f);
    }
  }

  // ==================== feature -> FC -> zmat ====================
  __syncthreads();   // all waves done with XcT (SPD) before aliasing
  float* featS = reinterpret_cast<float*>(XcT);          // 64*16 floats
  float* red2  = reinterpret_cast<float*>(XcT) + 1024;   // 256 floats
#pragma unroll
  for (int reg = 0; reg < 4; ++reg) {
    const int r = 16 * wave + 4 * g + reg;   // rows 62,63 written, never read
    featS[r * NOUT + mrow] = facc[reg];
  }
  __syncthreads();
  {
    const int n = tid >> 2, qq = tid & 3;
    float ps = 0.f;
    if (n < NC) {
      const float4* fw4 = reinterpret_cast<const float4*>(fc_w + n * (NC * NOUT));
      const float4* fs4 = reinterpret_cast<const float4*>(featS);
      for (int mm = 0; mm < 62; ++mm) {     // coalesced: 4 lanes cover 64B
        const float4 a = fs4[mm * 4 + qq];
        const float4 w = fw4[mm * 4 + qq];
        ps += a.x * w.x + a.y * w.y + a.z * w.z + a.w * w.w;
      }
    }
    red2[tid] = ps;
    __syncthreads();
    if (tid < NC) {
      zmat[(size_t)b * NC + tid] =
          red2[tid * 4] + red2[tid * 4 + 1] + red2[tid * 4 + 2] + red2[tid * 4 + 3] + fc_b[tid];
    }
  }
}

// =====================================================================
// Kernel D1: batch-norm statistics (unchanged).
// =====================================================================
__global__ __launch_bounds__(256) void k_bnstats(
    const float* __restrict__ zmat, const float* __restrict__ bn_g,
    const float* __restrict__ bn_b, float* __restrict__ bnp) {
  const int n = blockIdx.x;
  __shared__ float rs[256], rq[256];
  const int tid = threadIdx.x;
  float s = 0.f, sq = 0.f;
  for (int r = tid; r < NB; r += 256) {
    const float v = zmat[r * NC + n];
    s += v;
    sq += v * v;
  }
  rs[tid] = s; rq[tid] = sq;
  __syncthreads();
  for (int st = 128; st > 0; st >>= 1) {
    if (tid < st) { rs[tid] += rs[tid + st]; rq[tid] += rq[tid + st]; }
    __syncthreads();
  }
  if (tid == 0) {
    const float mean = rs[0] * (1.f / NB);
    const float var = rq[0] * (1.f / NB) - mean * mean;
    const float sc = bn_g[n] * rsqrtf(var + 1e-5f);
    bnp[2 * n] = sc;
    bnp[2 * n + 1] = bn_b[n] - mean * sc;
  }
}

// =====================================================================
// Kernel D2: BN + sigmoid -> output1; 62->2 FC -> output (unchanged).
// =====================================================================
__global__ __launch_bounds__(64) void k_bn_out(
    const float* __restrict__ zmat, const float* __restrict__ bnp,
    const float* __restrict__ fc4_w, const float* __restrict__ fc4_b,
    float* __restrict__ out) {
  const int b = blockIdx.x;
  const int lane = threadIdx.x;
  float o1 = 0.f;
  if (lane < NC) {
    float z = zmat[b * NC + lane];
    z = z * bnp[2 * lane] + bnp[2 * lane + 1];
    o1 = 1.f / (1.f + __expf(-z));
    out[b * NC + lane] = o1;
  }
  float p0 = (lane < NC) ? o1 * fc4_w[lane] : 0.f;
  float p1 = (lane < NC) ? o1 * fc4_w[NC + lane] : 0.f;
#pragma unroll
  for (int off = 32; off > 0; off >>= 1) {
    p0 += __shfl_down(p0, off, 64);
    p1 += __shfl_down(p1, off, 64);
  }
  if (lane == 0) {
    out[NB * NC + b * 2 + 0] = p0 + fc4_b[0];
    out[NB * NC + b * 2 + 1] = p1 + fc4_b[1];
  }
}

extern "C" void kernel_launch(void* const* d_in, const int* in_sizes, int n_in,
                              void* d_out, int out_size, void* d_ws, size_t ws_size,
                              hipStream_t stream) {
  const float* de      = (const float*)d_in[0];
  const float* pcc     = (const float*)d_in[1];
  const float* Aadj    = (const float*)d_in[2];
  // d_in[3] conv_w, d_in[4] conv_b: dead (gate cancels in trace-normalized SPD)
  const float* hconv_w = (const float*)d_in[5];
  const float* hconv_b = (const float*)d_in[6];
  const float* hlin_w  = (const float*)d_in[7];
  const float* hlin_b  = (const float*)d_in[8];
  const float* econv_w = (const float*)d_in[9];
  const float* econv_b = (const float*)d_in[10];
  const float* elin_w  = (const float*)d_in[11];
  const float* elin_b  = (const float*)d_in[12];
  const float* att_w1  = (const float*)d_in[13];
  const float* att_b1  = (const float*)d_in[14];
  const float* att_w2  = (const float*)d_in[15];
  const float* gc_w    = (const float*)d_in[16];
  const float* gc_b    = (const float*)d_in[17];
  // d_in[18] wpar: wnorm = exp(w)/exp(w) = 1 exactly for 1-element wpar
  const float* fc_w    = (const float*)d_in[19];
  const float* fc_b    = (const float*)d_in[20];
  const float* bn_g    = (const float*)d_in[21];
  const float* bn_b    = (const float*)d_in[22];
  const float* fc4_w   = (const float*)d_in[23];
  const float* fc4_b   = (const float*)d_in[24];

  float* ws   = (float*)d_ws;
  float* zmat = ws;                                  // 63,488 floats
  float* bnp  = zmat + (size_t)NB * NC;              // 128
  unsigned int* lwHg = (unsigned int*)(bnp + 128);   // 4,096 u32
  unsigned int* w1Hg = lwHg + 4096;                  // 512 u32
  float* rsumG = (float*)(w1Hg + 512);               // 128

  k_init<<<1, 256, 0, stream>>>(hlin_w, elin_w, att_w1, lwHg, w1Hg, rsumG);
  k_fused<<<NB, 256, 0, stream>>>(pcc, Aadj, lwHg, w1Hg, rsumG,
      hconv_w, hconv_b, hlin_b,
      econv_w, econv_b, elin_b,
      att_b1, att_w2,
      de, gc_w, gc_b, fc_w, fc_b, zmat);
  k_bnstats<<<NC, 256, 0, stream>>>(zmat, bn_g, bn_b, bnp);
  k_bn_out<<<NB, 64, 0, stream>>>(zmat, bnp, fc4_w, fc4_b, (float*)d_out);
}